// Round 16
// baseline (454.617 us; speedup 1.0000x reference)
//
#include <hip/hip_runtime.h>
#include <hip/hip_bf16.h>
#include <math.h>

typedef __hip_bfloat16 bf16;
typedef __bf16 v8bf __attribute__((ext_vector_type(8)));
typedef float v4f __attribute__((ext_vector_type(4)));

#define BN_SCALE 0.9999950000374997f
#define NPTS 1024
#define NB 4
#define CH5 ((size_t)4 * 1024 * 512)   // conv5 partial-chunk stride (floats)

__device__ __forceinline__ float b2f(bf16 v) { return __bfloat162float(v); }
__device__ __forceinline__ bf16 f2b(float v) { return __float2bfloat16(v); }
__device__ __forceinline__ float ldw(const void* p, size_t i, int isf) {
    return isf ? ((const float*)p)[i] : b2f(((const bf16*)p)[i]);
}
__device__ __forceinline__ unsigned ordf(float f) {
    unsigned u = __float_as_uint(f);
    return (u & 0x80000000u) ? ~u : (u | 0x80000000u);
}
__device__ __forceinline__ float iordf(unsigned u) {
    return (u & 0x80000000u) ? __uint_as_float(u ^ 0x80000000u) : __uint_as_float(~u);
}

// per-block dtype detect from first 512 shorts of x (fp32 ~113/256 implausible, bf16 ~0)
__device__ __forceinline__ int detect_isf(const void* xraw, int* cnt) {
    const unsigned short* u = (const unsigned short*)xraw;
    int t = threadIdx.x, c = 0;
    for (int i = t; i < 512; i += 256) {
        unsigned short v = u[i];
        int e = (v >> 7) & 0xFF;
        int m = v & 0x7F;
        if (e == 0xFF || e >= 141 || (e == 0 && m != 0)) c++;
    }
    cnt[t] = c;
    __syncthreads();
    for (int off = 128; off > 0; off >>= 1) {
        if (t < off) cnt[t] += cnt[t + off];
        __syncthreads();
    }
    int isf = (cnt[0] > 30) ? 1 : 0;
    __syncthreads();
    return isf;
}

// ---------------- fused prep: dtype flag + pooled init + weight splits + x pad + sq ----------------
__global__ void k_prep(const void* __restrict__ W1, const void* __restrict__ W2,
                       const void* __restrict__ W3, const void* __restrict__ W4,
                       const void* __restrict__ W5, const void* __restrict__ x,
                       bf16* __restrict__ Whi, bf16* __restrict__ Wlo,
                       bf16* __restrict__ xph, bf16* __restrict__ xpl, float* __restrict__ sq,
                       int* __restrict__ flag, unsigned* __restrict__ pooledU) {
    __shared__ int cnt[256];
    int isf = detect_isf(x, cnt);
    if (blockIdx.x == 0) {
        if (threadIdx.x == 0) *flag = isf;
        for (int i = threadIdx.x; i < 2048; i += 256) pooledU[i] = 0u;  // 0 < ordf(any finite)
    }
    int idx = blockIdx.x * 256 + threadIdx.x;
    if (idx < 839680) {
        const void* src; int C, O, Kpad, two, local;
        if (idx < 4096)        { src = W1; C = 3;   O = 64;  Kpad = 32;  two = 1; local = idx; }
        else if (idx < 20480)  { src = W2; C = 64;  O = 128; Kpad = 64;  two = 1; local = idx - 4096; }
        else if (idx < 86016)  { src = W3; C = 128; O = 256; Kpad = 128; two = 1; local = idx - 20480; }
        else if (idx < 348160) { src = W4; C = 256; O = 512; Kpad = 256; two = 1; local = idx - 86016; }
        else                   { src = W5; C = 960; O = 512; Kpad = 960; two = 0; local = idx - 348160; }
        int r = local / Kpad, c = local % Kpad;
        float wv = 0.f;
        if (c < C) {
            size_t off;
            if (two) off = (r < O) ? (size_t)r * 2 * C + c : (size_t)(r - O) * 2 * C + C + c;
            else     off = (size_t)r * C + c;
            wv = ldw(src, off, isf);
        }
        bf16 h = f2b(wv);
        Whi[idx] = h;
        Wlo[idx] = f2b(wv - b2f(h));
    } else if (idx < 843776) {
        int p = idx - 839680;       // point index: z*1024 + n
        int z = p >> 10, n = p & 1023;
        bf16* ph = xph + (size_t)z * NPTS * 32;
        bf16* pl = xpl + (size_t)z * NPTS * 32;
        float s = 0.f;
        for (int c = 0; c < 32; c++) {
            float v = (c < 3) ? ldw(x, (size_t)z * NPTS * 3 + n * 3 + c, isf) : 0.f;
            bf16 h = f2b(v);
            ph[n * 32 + c] = h;
            pl[n * 32 + c] = f2b(v - b2f(h));
            s += v * v;
        }
        sq[z * NPTS + n] = s;
    }
}

// ---- conflict-free LDS layout: k-quad-major [kq][row][8], XOR-swizzled ----
__device__ __forceinline__ int lidx(int plane, int row) {
    return ((((plane << 7) | row)) ^ (plane << 1)) << 3;
}
// staged fill split: global->regs (issue early) then regs->LDS (write late) for dbuf pipelining
struct St2 { float4 a, b; };
__device__ __forceinline__ St2 ldStage(const bf16* src, int ld) {
    int t = threadIdx.x; int r = t >> 2, kq = t & 3;
    St2 s;
    s.a = *(const float4*)(src + (size_t)r * ld + kq * 8);
    s.b = *(const float4*)(src + (size_t)(r + 64) * ld + kq * 8);
    return s;
}
__device__ __forceinline__ void stStage(bf16* dst, const St2& s) {
    int t = threadIdx.x; int r = t >> 2, kq = t & 3;
    *(float4*)(dst + lidx(kq, r)) = s.a;
    *(float4*)(dst + lidx(kq, r + 64)) = s.b;
}
// single-shot fill (conv5 keeps the proven 2-barrier structure)
__device__ __forceinline__ void fill128(bf16* dst, const bf16* src, int ld) {
    int t = threadIdx.x;
    int r = t >> 2, kq = t & 3;
    *(float4*)(dst + lidx(kq, r))      = *(const float4*)(src + (size_t)r * ld + kq * 8);
    *(float4*)(dst + lidx(kq, r + 64)) = *(const float4*)(src + (size_t)(r + 64) * ld + kq * 8);
}
// MFMA fragment: sub-tile 'sub' (16 rows of 128), lane l: row=sub*16+(l&15), k=(l>>4)*8..+7
__device__ __forceinline__ v8bf ldf(const bf16* tile, int sub, int l) {
    return *(const v8bf*)(tile + lidx(l >> 4, sub * 16 + (l & 15)));
}

#define TSTRIDE 129   // f32 transpose tile stride (128+1: conflict-free row reads)

// ---------------- fused layer stage A: dist (upper-tri 128x128 tiles) + st ----------------
// MEASUREMENT: baseGrid decode (i = blockIdx.x % baseGrid); replicas rewrite identical values
// (idempotent kernel) -> benign duplicate writes, amplified per-dispatch dur for profiling.
__global__ __launch_bounds__(256) void k_layer_a(const bf16* __restrict__ Xhi, const bf16* __restrict__ Xlo,
                                                 int ld, int Kpad, size_t xstride,
                                                 const bf16* __restrict__ Whi, const bf16* __restrict__ Wlo,
                                                 int O, const float* __restrict__ sqg,
                                                 float* __restrict__ Dg, float* __restrict__ Pg,
                                                 const int* __restrict__ flag, int baseGrid) {
    int i = blockIdx.x % baseGrid;
    int z = (i >> 1) & 3;
    int bi = ((i >> 3) << 1) | (i & 1);
    const bf16* Xh = Xhi + (size_t)z * xstride;
    const bf16* Xl = Xlo + (size_t)z * xstride;
    __shared__ alignas(16) char smem[128 * TSTRIDE * 4];   // 66,048 B >= 64 KB staging
    bf16* Ah = (bf16*)smem;                 // [2][4096]
    bf16* Al = (bf16*)(smem + 16384);       // [2][4096]
    bf16* Bh = (bf16*)(smem + 32768);       // [2][4096]
    bf16* Bl = (bf16*)(smem + 49152);       // [2][4096]
    int w = threadIdx.x >> 6, l = threadIdx.x & 63;
    int wr = w >> 1, wc = w & 1;
    int quad = l >> 4, col = l & 15;
    v4f zero = {0.f, 0.f, 0.f, 0.f};
    v4f acc[4][4] = {{zero, zero, zero, zero}, {zero, zero, zero, zero},
                     {zero, zero, zero, zero}, {zero, zero, zero, zero}};

    if (bi < 36) {
        // ---- dist tile: triangular decode over 8x8, bx >= by ----
        int bx = 0;
        while ((((bx + 1) * (bx + 2)) >> 1) <= bi) bx++;
        int by = bi - ((bx * (bx + 1)) >> 1);
        const float* sq = sqg + z * NPTS;
        float* D = Dg + (size_t)z * NPTS * NPTS;
        int n0 = by * 128, m0 = bx * 128;
        const bf16* pAn = Xh + (size_t)n0 * ld;
        const bf16* pAm = Xh + (size_t)m0 * ld;
        const bf16* pLn = Xl + (size_t)n0 * ld;
        const bf16* pLm = Xl + (size_t)m0 * ld;
        St2 sA = ldStage(pAn, ld), sB = ldStage(pAm, ld);
        St2 sC = ldStage(pLn, ld), sD = ldStage(pLm, ld);
        stStage(Ah, sA); stStage(Bh, sB);
        stStage(Al, sC); stStage(Bl, sD);
        __syncthreads();
        int cur = 0;
        for (int k0 = 0; k0 < Kpad; k0 += 32) {
            bool more = (k0 + 32 < Kpad);
            if (more) {
                sA = ldStage(pAn + k0 + 32, ld);
                sB = ldStage(pAm + k0 + 32, ld);
                sC = ldStage(pLn + k0 + 32, ld);
                sD = ldStage(pLm + k0 + 32, ld);
            }
            v8bf ah[4], al[4];
#pragma unroll
            for (int mi = 0; mi < 4; mi++) {
                ah[mi] = ldf(Ah + cur * 4096, wr * 4 + mi, l);
                al[mi] = ldf(Al + cur * 4096, wr * 4 + mi, l);
            }
#pragma unroll
            for (int ni = 0; ni < 4; ni++) {
                v8bf bh = ldf(Bh + cur * 4096, wc * 4 + ni, l);
                v8bf bl = ldf(Bl + cur * 4096, wc * 4 + ni, l);
#pragma unroll
                for (int mi = 0; mi < 4; mi++) {
                    acc[mi][ni] = __builtin_amdgcn_mfma_f32_16x16x32_bf16(ah[mi], bh, acc[mi][ni], 0, 0, 0);
                    acc[mi][ni] = __builtin_amdgcn_mfma_f32_16x16x32_bf16(ah[mi], bl, acc[mi][ni], 0, 0, 0);
                    acc[mi][ni] = __builtin_amdgcn_mfma_f32_16x16x32_bf16(al[mi], bh, acc[mi][ni], 0, 0, 0);
                }
            }
            if (more) {
                stStage(Ah + (cur ^ 1) * 4096, sA); stStage(Bh + (cur ^ 1) * 4096, sB);
                stStage(Al + (cur ^ 1) * 4096, sC); stStage(Bl + (cur ^ 1) * 4096, sD);
            }
            __syncthreads();
            cur ^= 1;
        }
        int rb = n0 + wr * 64 + quad * 4;
        int cb = m0 + wc * 64 + col;
        int rloc = wr * 64 + quad * 4;       // row index within tile
        int cloc = wc * 64 + col;            // col index within tile
        float* Tt = (float*)smem;            // [128][TSTRIDE] f32, aliases dead staging
        float sm[4];
#pragma unroll
        for (int ni = 0; ni < 4; ni++) sm[ni] = sq[cb + ni * 16];
#pragma unroll
        for (int mi = 0; mi < 4; mi++) {
#pragma unroll
            for (int r = 0; r < 4; r++) {
                int row = rb + mi * 16 + r;
                float sn = sq[row];
#pragma unroll
                for (int ni = 0; ni < 4; ni++) {
                    float d = 2.f * acc[mi][ni][r] - sn - sm[ni];
                    D[(size_t)row * NPTS + cb + ni * 16] = d;
                    if (bx != by)
                        Tt[(cloc + ni * 16) * TSTRIDE + rloc + mi * 16 + r] = d;
                }
            }
        }
        if (bx != by) {                      // coalesced transposed write of the mirror
            __syncthreads();
            int t = threadIdx.x;
            int rl = t & 127, ch = t >> 7;
            float* Dm = D + (size_t)m0 * NPTS + n0;
#pragma unroll 4
            for (int it = 0; it < 64; it++) {
                int cl = it * 2 + ch;
                Dm[(size_t)cl * NPTS + rl] = Tt[cl * TSTRIDE + rl];
            }
        }
    } else {
        // ---- st tile: P[point m, weight-row n] over 2O cols ----
        int isf = *flag;
        int nCol = (2 * O) >> 7;
        int s = bi - 36;
        int n0 = (s % nCol) * 128;   // weight-row tile (over 2O)
        int m0 = (s / nCol) * 128;   // point tile (over 1024)
        int N2 = 2 * O;
        float* P = Pg + (size_t)z * NPTS * N2;
        const bf16* pXh = Xh + (size_t)m0 * ld;
        const bf16* pXl = Xl + (size_t)m0 * ld;
        const bf16* pWh = Whi + (size_t)n0 * Kpad;
        const bf16* pWl = Wlo + (size_t)n0 * Kpad;
        St2 sA = ldStage(pXh, ld), sC = ldStage(pXl, ld);
        St2 sB = ldStage(pWh, Kpad), sD;
        if (isf) sD = ldStage(pWl, Kpad);
        stStage(Ah, sA); stStage(Al, sC); stStage(Bh, sB);
        if (isf) stStage(Bl, sD);
        __syncthreads();
        int cur = 0;
        for (int k0 = 0; k0 < Kpad; k0 += 32) {
            bool more = (k0 + 32 < Kpad);
            if (more) {
                sA = ldStage(pXh + k0 + 32, ld);
                sC = ldStage(pXl + k0 + 32, ld);
                sB = ldStage(pWh + k0 + 32, Kpad);
                if (isf) sD = ldStage(pWl + k0 + 32, Kpad);
            }
            v8bf ah[4], al[4];
#pragma unroll
            for (int mi = 0; mi < 4; mi++) {
                ah[mi] = ldf(Ah + cur * 4096, wr * 4 + mi, l);
                al[mi] = ldf(Al + cur * 4096, wr * 4 + mi, l);
            }
#pragma unroll
            for (int ni = 0; ni < 4; ni++) {
                v8bf bh = ldf(Bh + cur * 4096, wc * 4 + ni, l);
#pragma unroll
                for (int mi = 0; mi < 4; mi++) {
                    acc[mi][ni] = __builtin_amdgcn_mfma_f32_16x16x32_bf16(ah[mi], bh, acc[mi][ni], 0, 0, 0);
                    acc[mi][ni] = __builtin_amdgcn_mfma_f32_16x16x32_bf16(al[mi], bh, acc[mi][ni], 0, 0, 0);
                }
                if (isf) {
                    v8bf bl = ldf(Bl + cur * 4096, wc * 4 + ni, l);
#pragma unroll
                    for (int mi = 0; mi < 4; mi++)
                        acc[mi][ni] = __builtin_amdgcn_mfma_f32_16x16x32_bf16(ah[mi], bl, acc[mi][ni], 0, 0, 0);
                }
            }
            if (more) {
                stStage(Ah + (cur ^ 1) * 4096, sA); stStage(Al + (cur ^ 1) * 4096, sC);
                stStage(Bh + (cur ^ 1) * 4096, sB);
                if (isf) stStage(Bl + (cur ^ 1) * 4096, sD);
            }
            __syncthreads();
            cur ^= 1;
        }
        int rb = m0 + wr * 64 + quad * 4;
        int cb = n0 + wc * 64 + col;
#pragma unroll
        for (int mi = 0; mi < 4; mi++)
#pragma unroll
            for (int r = 0; r < 4; r++) {
                int row = rb + mi * 16 + r;
#pragma unroll
                for (int ni = 0; ni < 4; ni++)
                    P[(size_t)row * N2 + cb + ni * 16] = acc[mi][ni][r];
            }
    }
}

// ---- argmax combine via DPP (VALU pipe) ----
template<int CTRL>
__device__ __forceinline__ void dpp_step(float& bv, int& bi) {
    int ov_i = __builtin_amdgcn_update_dpp(__float_as_int(bv), __float_as_int(bv), CTRL, 0xF, 0xF, false);
    int oi   = __builtin_amdgcn_update_dpp(bi, bi, CTRL, 0xF, 0xF, false);
    float ov = __int_as_float(ov_i);
    if (ov > bv || (ov == bv && oi < bi)) { bv = ov; bi = oi; }
}
#define PICK(va, ja, vb, jb, vo, jo) { bool t_ = (vb) > (va); vo = t_ ? (vb) : (va); jo = t_ ? (jb) : (ja); }

// ---------------- fused stage B: top-20 + gather-max, WAVE-PER-ROW end-to-end ----------------
// MEASUREMENT: baseGrid decode; replicas rewrite identical values (idempotent).
__global__ __launch_bounds__(256) void k_layer_b(const float* __restrict__ Dg, const float* __restrict__ Pg,
                                                 const void* __restrict__ g, const void* __restrict__ bias,
                                                 int O, bf16* __restrict__ xhOut, bf16* __restrict__ xlOut,
                                                 float* __restrict__ sqOut, int writeSq,
                                                 const int* __restrict__ flag, int baseGrid) {
    __shared__ int ids[4][20];
    int isf = *flag;
    int i = blockIdx.x % baseGrid;
    int z = (i >> 1) & 3;
    int local = ((i >> 3) << 1) | (i & 1);
    int tid = threadIdx.x;
    int wq = tid >> 6, l = tid & 63;
    int row = local * 4 + wq;

    {
        const float* Dr = Dg + (size_t)z * NPTS * NPTS + (size_t)row * NPTS;
        float v[16];
#pragma unroll
        for (int jj = 0; jj < 4; jj++) {
            float4 f4 = *(const float4*)(Dr + jj * 256 + l * 4);
            v[jj * 4 + 0] = f4.x; v[jj * 4 + 1] = f4.y;
            v[jj * 4 + 2] = f4.z; v[jj * 4 + 3] = f4.w;
        }
        float bmv[4]; int bmj[4];
#pragma unroll
        for (int gg = 0; gg < 4; gg++) {
            float a0, a1; int j0, j1;
            PICK(v[4 * gg + 0], 4 * gg + 0, v[4 * gg + 1], 4 * gg + 1, a0, j0);
            PICK(v[4 * gg + 2], 4 * gg + 2, v[4 * gg + 3], 4 * gg + 3, a1, j1);
            PICK(a0, j0, a1, j1, bmv[gg], bmj[gg]);
        }
        for (int s = 0; s < 20; s++) {
            float t0, t1, bv; int s0, s1, bj;
            PICK(bmv[0], bmj[0], bmv[1], bmj[1], t0, s0);
            PICK(bmv[2], bmj[2], bmv[3], bmj[3], t1, s1);
            PICK(t0, s0, t1, s1, bv, bj);
            int bi = (bj >> 2) * 256 + l * 4 + (bj & 3);
            dpp_step<0xB1>(bv, bi);    // quad_perm xor1
            dpp_step<0x4E>(bv, bi);    // quad_perm xor2
            dpp_step<0x124>(bv, bi);   // row_ror:4
            dpp_step<0x128>(bv, bi);   // row_ror:8
            dpp_step<0x142>(bv, bi);   // row_bcast15
            dpp_step<0x143>(bv, bi);   // row_bcast31 -> lane63 global
            int bii = __builtin_amdgcn_readlane(bi, 63);
            if (l == 0) ids[wq][s] = bii;
            if (((bii >> 2) & 63) == l) {
                int ej = (bii >> 8) * 4 + (bii & 3);
                int eg = ej >> 2, ek = ej & 3;
#pragma unroll
                for (int gg = 0; gg < 4; gg++) if (gg == eg) {
#pragma unroll
                    for (int kk = 0; kk < 4; kk++)
                        if (kk == ek) v[4 * gg + kk] = -__builtin_inff();
                    float a0, a1; int j0, j1;
                    PICK(v[4 * gg + 0], 4 * gg + 0, v[4 * gg + 1], 4 * gg + 1, a0, j0);
                    PICK(v[4 * gg + 2], 4 * gg + 2, v[4 * gg + 3], 4 * gg + 3, a1, j1);
                    PICK(a0, j0, a1, j1, bmv[gg], bmj[gg]);
                }
            }
        }
    }

    int N2 = 2 * O;
    const float* P = Pg + (size_t)z * NPTS * N2;
    int offj[20];
#pragma unroll
    for (int j = 0; j < 20; j++)
        offj[j] = __builtin_amdgcn_readfirstlane(ids[wq][j]) * N2;
    int n = row;
    const float* Pn = P + (size_t)n * N2;
    float tot = 0.f;
    int nc = O >> 6;
    for (int c = 0; c < nc; c++) {
        int o = c * 64 + l;
        float tv = Pn[O + o] - Pn[o];
        float mx = -__builtin_inff(), mn = __builtin_inff();
#pragma unroll
        for (int j = 0; j < 20; j++) {
            float vv = P[offj[j] + o];
            mx = fmaxf(mx, vv);
            mn = fminf(mn, vv);
        }
        float scl = ldw(g, o, isf) * BN_SCALE;
        float bb = ldw(bias, o, isf);
        float base = (scl >= 0.f ? mx : mn) + tv;
        float accv = base * scl + bb;
        accv = accv > 0.f ? accv : 0.2f * accv;
        bf16 hi = f2b(accv);
        bf16 lo = f2b(accv - b2f(hi));
        xhOut[(size_t)z * NPTS * 960 + (size_t)n * 960 + o] = hi;
        xlOut[(size_t)z * NPTS * 960 + (size_t)n * 960 + o] = lo;
        if (writeSq) {
            float xv = b2f(hi) + b2f(lo);
            float s2 = xv * xv;
#pragma unroll
            for (int off = 32; off > 0; off >>= 1) s2 += __shfl_down(s2, off);
            if (l == 0) tot += s2;
        }
    }
    if (writeSq && l == 0) sqOut[z * NPTS + row] = tot;
}

// ---------------- conv5 via MFMA, K-split x6 (chunks of 160) -> f32 partials ----------------
// MEASUREMENT: baseGrid decode; replicas rewrite identical values (disjoint per (ks,z,tile)).
__global__ __launch_bounds__(256) void k_conv5(const bf16* __restrict__ Xhi, const bf16* __restrict__ Xlo,
                                               const bf16* __restrict__ Whi, const bf16* __restrict__ Wlo,
                                               float* __restrict__ P5,
                                               const int* __restrict__ flag, int baseGrid) {
    int isf = *flag;
    int i = blockIdx.x % baseGrid;
    int z = (i >> 1) & 3;
    int rest = ((i >> 3) << 1) | (i & 1);
    int ks = rest >> 5;
    int tile = rest & 31;
    int m0 = (tile >> 2) * 128, o0 = (tile & 3) * 128;
    const bf16* Xh = Xhi + (size_t)z * NPTS * 960;
    const bf16* Xl = Xlo + (size_t)z * NPTS * 960;
    __shared__ alignas(16) bf16 Ah[4096], Al[4096], Bh[4096], Bl[4096];
    int w = threadIdx.x >> 6, l = threadIdx.x & 63;
    int wr = w >> 1, wc = w & 1;
    int quad = l >> 4, col = l & 15;
    v4f zero = {0.f, 0.f, 0.f, 0.f};
    v4f acc[4][4] = {{zero, zero, zero, zero}, {zero, zero, zero, zero},
                     {zero, zero, zero, zero}, {zero, zero, zero, zero}};
    int kbeg = ks * 160, kend = kbeg + 160;
    for (int k0 = kbeg; k0 < kend; k0 += 32) {
        __syncthreads();
        fill128(Ah, Xh + (size_t)m0 * 960 + k0, 960);
        fill128(Al, Xl + (size_t)m0 * 960 + k0, 960);
        fill128(Bh, Whi + (size_t)o0 * 960 + k0, 960);
        if (isf) fill128(Bl, Wlo + (size_t)o0 * 960 + k0, 960);
        __syncthreads();
        v8bf ah[4], al[4];
#pragma unroll
        for (int mi = 0; mi < 4; mi++) {
            ah[mi] = ldf(Ah, wr * 4 + mi, l);
            al[mi] = ldf(Al, wr * 4 + mi, l);
        }
#pragma unroll
        for (int ni = 0; ni < 4; ni++) {
            v8bf bh = ldf(Bh, wc * 4 + ni, l);
#pragma unroll
            for (int mi = 0; mi < 4; mi++) {
                acc[mi][ni] = __builtin_amdgcn_mfma_f32_16x16x32_bf16(ah[mi], bh, acc[mi][ni], 0, 0, 0);
                acc[mi][ni] = __builtin_amdgcn_mfma_f32_16x16x32_bf16(al[mi], bh, acc[mi][ni], 0, 0, 0);
            }
            if (isf) {
                v8bf bl = ldf(Bl, wc * 4 + ni, l);
#pragma unroll
                for (int mi = 0; mi < 4; mi++)
                    acc[mi][ni] = __builtin_amdgcn_mfma_f32_16x16x32_bf16(ah[mi], bl, acc[mi][ni], 0, 0, 0);
            }
        }
    }
    float* Pw = P5 + (size_t)ks * CH5 + (size_t)z * NPTS * 512;
    int rb = m0 + wr * 64 + quad * 4;
    int cb = o0 + wc * 64 + col;
#pragma unroll
    for (int mi = 0; mi < 4; mi++)
#pragma unroll
        for (int r = 0; r < 4; r++) {
            int row = rb + mi * 16 + r;
#pragma unroll
            for (int ni = 0; ni < 4; ni++)
                Pw[(size_t)row * 512 + cb + ni * 16] = acc[mi][ni][r];
        }
}

// ---------------- pool5: sum 6 K-chunks + affine + lrelu + max over rows -> pooled ----------------
__global__ __launch_bounds__(256) void k_pool5(const float* __restrict__ P5,
                                               const void* __restrict__ g, const void* __restrict__ bias,
                                               unsigned* __restrict__ pooledU,
                                               const int* __restrict__ flag) {
    __shared__ float red2[128];
    int isf = *flag;
    int i = blockIdx.x;
    int z = (i >> 1) & 3;
    int rest = ((i >> 3) << 1) | (i & 1);
    int oc = (rest & 3) * 128, mc = (rest >> 2) * 32;
    int t = threadIdx.x;
    int c = t & 127, h = t >> 7;
    int o = oc + c;
    float scl = ldw(g, o, isf) * BN_SCALE;
    float bb = ldw(bias, o, isf);
    const float* p0 = P5 + (size_t)z * NPTS * 512 + (size_t)(mc + h * 16) * 512 + o;
    float ym = -__builtin_inff();
    for (int r = 0; r < 16; r++) {
        const float* p = p0 + (size_t)r * 512;
        float s = p[0];
#pragma unroll
        for (int ks = 1; ks < 6; ks++) s += p[(size_t)ks * CH5];
        float v = s * scl + bb;
        v = v > 0.f ? v : 0.2f * v;
        ym = fmaxf(ym, v);
    }
    if (h == 1) red2[c] = ym;
    __syncthreads();
    if (h == 0) {
        float m = fmaxf(ym, red2[c]);
        atomicMax(&pooledU[z * 512 + o], ordf(m));
    }
}

// ---------------- final linear: coalesced wave-per-output ----------------
__global__ void k_final(const unsigned* __restrict__ pooledU, const void* __restrict__ We,
                        void* __restrict__ out, const int* __restrict__ flag) {
    __shared__ float p[512];
    int isf = *flag;
    int b = blockIdx.x >> 2, fb = blockIdx.x & 3;
    int t = threadIdx.x, w = t >> 6, l = t & 63;
    for (int i = t; i < 512; i += 256) p[i] = iordf(pooledU[b * 512 + i]);
    __syncthreads();
    for (int it = 0; it < 16; it++) {
        int f = fb * 64 + w * 16 + it;
        float s = 0.f;
        size_t base = (size_t)f * 512 + l * 8;
#pragma unroll
        for (int j = 0; j < 8; j++) s += p[l * 8 + j] * ldw(We, base + j, isf);
#pragma unroll
        for (int off = 32; off > 0; off >>= 1) s += __shfl_down(s, off);
        if (l == 0) {
            if (isf) ((float*)out)[b * 256 + f] = s;
            else     ((bf16*)out)[b * 256 + f] = f2b(s);
        }
    }
}

extern "C" void kernel_launch(void* const* d_in, const int* in_sizes, int n_in,
                              void* d_out, int out_size, void* d_ws, size_t ws_size,
                              hipStream_t stream) {
    const void* x  = d_in[0];
    const void* Wl[4] = { d_in[1], d_in[4], d_in[7], d_in[10] };
    const void* gl[4] = { d_in[2], d_in[5], d_in[8], d_in[11] };
    const void* bl[4] = { d_in[3], d_in[6], d_in[9], d_in[12] };
    const void* W5 = d_in[13];
    const void* g5 = d_in[14];
    const void* b5 = d_in[15];
    const void* We = d_in[16];

    // workspace layout (bytes), ~103.9 MB total
    char* base = (char*)d_ws;
    bf16*     xc_hi   = (bf16*)(base);                  // 7,864,320
    bf16*     xc_lo   = (bf16*)(base + 7864320);        // 7,864,320
    bf16*     xpadh   = (bf16*)(base + 15728640);       // 262,144
    bf16*     xpadl   = (bf16*)(base + 15990784);       // 262,144
    float*    Dbuf    = (float*)(base + 16252928);      // 16,777,216
    float*    Pbuf    = (float*)(base + 33030144);      // 16,777,216
    bf16*     Whi     = (bf16*)(base + 49807360);       // 1,679,360
    bf16*     Wlo     = (bf16*)(base + 51486720);       // 1,679,360
    unsigned* pooledU = (unsigned*)(base + 53493760);   // 8,192
    float*    sq      = (float*)(base + 53501952);      // 16,384
    int*      flag    = (int*)(base + 53518336);        // 4
    float*    P5      = (float*)(base + 53520384);      // 50,331,648 (6 x 8 MB conv5 partials)

    const int Kpad[4]   = { 32, 64, 128, 256 };
    const int Os[4]     = { 64, 128, 256, 512 };
    const int Woff[5]   = { 0, 4096, 20480, 86016, 348160 };
    const int colIn[4]  = { 0, 0, 64, 192 };
    const int colOut[4] = { 0, 64, 192, 448 };

    k_prep<<<3296, 256, 0, stream>>>(Wl[0], Wl[1], Wl[2], Wl[3], W5, x,
                                     Whi, Wlo, xpadh, xpadl, sq, flag, pooledU);

    for (int l = 0; l < 4; l++) {
        int O = Os[l];
        int nCol = (2 * O) >> 7;
        int nBlk = 36 + 8 * nCol;  // 44/52/68/100 -> *4 divisible by 8 for XCD decode
        const bf16* Xh = (l == 0) ? xpadh : (xc_hi + colIn[l]);
        const bf16* Xl = (l == 0) ? xpadl : (xc_lo + colIn[l]);
        int ld = (l == 0) ? 32 : 960;
        size_t xstr = (l == 0) ? (size_t)NPTS * 32 : (size_t)NPTS * 960;
        int baseA = nBlk * NB;
        int gridA = (l == 3) ? baseA * 4 : baseA;     // MEASUREMENT: amplify L4 layer_a x4
        k_layer_a<<<gridA, 256, 0, stream>>>(
            Xh, Xl, ld, Kpad[l], xstr, Whi + Woff[l], Wlo + Woff[l], O, sq, Dbuf, Pbuf, flag, baseA);
        int gridB = (l == 0 || l == 3) ? 4096 : 1024; // MEASUREMENT: amplify L1/L4 layer_b x4
        k_layer_b<<<gridB, 256, 0, stream>>>(
            Dbuf, Pbuf, gl[l], bl[l], O, xc_hi + colOut[l], xc_lo + colOut[l], sq, l < 3, flag, 1024);
    }
    k_conv5<<<3072, 256, 0, stream>>>(xc_hi, xc_lo, Whi + Woff[4], Wlo + Woff[4], P5, flag, 768);  // x4
    k_pool5<<<512, 256, 0, stream>>>(P5, g5, b5, pooledU, flag);
    k_final<<<16, 256, 0, stream>>>(pooledU, We, d_out, flag);
}

// Round 17
// 295.067 us; speedup vs baseline: 1.5407x; 1.5407x over previous
//
#include <hip/hip_runtime.h>
#include <hip/hip_bf16.h>
#include <math.h>

typedef __hip_bfloat16 bf16;
typedef __bf16 v8bf __attribute__((ext_vector_type(8)));
typedef float v4f __attribute__((ext_vector_type(4)));

#define BN_SCALE 0.9999950000374997f
#define NPTS 1024
#define NB 4
#define CH5 ((size_t)4 * 1024 * 512)   // conv5 partial-chunk stride (floats)

__device__ __forceinline__ float b2f(bf16 v) { return __bfloat162float(v); }
__device__ __forceinline__ bf16 f2b(float v) { return __float2bfloat16(v); }
__device__ __forceinline__ float ldw(const void* p, size_t i, int isf) {
    return isf ? ((const float*)p)[i] : b2f(((const bf16*)p)[i]);
}
__device__ __forceinline__ unsigned ordf(float f) {
    unsigned u = __float_as_uint(f);
    return (u & 0x80000000u) ? ~u : (u | 0x80000000u);
}
__device__ __forceinline__ float iordf(unsigned u) {
    return (u & 0x80000000u) ? __uint_as_float(u ^ 0x80000000u) : __uint_as_float(~u);
}

// per-block dtype detect from first 512 shorts of x (fp32 ~113/256 implausible, bf16 ~0)
__device__ __forceinline__ int detect_isf(const void* xraw, int* cnt) {
    const unsigned short* u = (const unsigned short*)xraw;
    int t = threadIdx.x, c = 0;
    for (int i = t; i < 512; i += 256) {
        unsigned short v = u[i];
        int e = (v >> 7) & 0xFF;
        int m = v & 0x7F;
        if (e == 0xFF || e >= 141 || (e == 0 && m != 0)) c++;
    }
    cnt[t] = c;
    __syncthreads();
    for (int off = 128; off > 0; off >>= 1) {
        if (t < off) cnt[t] += cnt[t + off];
        __syncthreads();
    }
    int isf = (cnt[0] > 30) ? 1 : 0;
    __syncthreads();
    return isf;
}

// ---------------- fused prep: dtype flag + pooled init + weight splits + x pad + sq ----------------
__global__ void k_prep(const void* __restrict__ W1, const void* __restrict__ W2,
                       const void* __restrict__ W3, const void* __restrict__ W4,
                       const void* __restrict__ W5, const void* __restrict__ x,
                       bf16* __restrict__ Whi, bf16* __restrict__ Wlo,
                       bf16* __restrict__ xph, bf16* __restrict__ xpl, float* __restrict__ sq,
                       int* __restrict__ flag, unsigned* __restrict__ pooledU) {
    __shared__ int cnt[256];
    int isf = detect_isf(x, cnt);
    if (blockIdx.x == 0) {
        if (threadIdx.x == 0) *flag = isf;
        for (int i = threadIdx.x; i < 2048; i += 256) pooledU[i] = 0u;  // 0 < ordf(any finite)
    }
    int idx = blockIdx.x * 256 + threadIdx.x;
    if (idx < 839680) {
        const void* src; int C, O, Kpad, two, local;
        if (idx < 4096)        { src = W1; C = 3;   O = 64;  Kpad = 32;  two = 1; local = idx; }
        else if (idx < 20480)  { src = W2; C = 64;  O = 128; Kpad = 64;  two = 1; local = idx - 4096; }
        else if (idx < 86016)  { src = W3; C = 128; O = 256; Kpad = 128; two = 1; local = idx - 20480; }
        else if (idx < 348160) { src = W4; C = 256; O = 512; Kpad = 256; two = 1; local = idx - 86016; }
        else                   { src = W5; C = 960; O = 512; Kpad = 960; two = 0; local = idx - 348160; }
        int r = local / Kpad, c = local % Kpad;
        float wv = 0.f;
        if (c < C) {
            size_t off;
            if (two) off = (r < O) ? (size_t)r * 2 * C + c : (size_t)(r - O) * 2 * C + C + c;
            else     off = (size_t)r * C + c;
            wv = ldw(src, off, isf);
        }
        bf16 h = f2b(wv);
        Whi[idx] = h;
        Wlo[idx] = f2b(wv - b2f(h));
    } else if (idx < 843776) {
        int p = idx - 839680;       // point index: z*1024 + n
        int z = p >> 10, n = p & 1023;
        bf16* ph = xph + (size_t)z * NPTS * 32;
        bf16* pl = xpl + (size_t)z * NPTS * 32;
        float s = 0.f;
        for (int c = 0; c < 32; c++) {
            float v = (c < 3) ? ldw(x, (size_t)z * NPTS * 3 + n * 3 + c, isf) : 0.f;
            bf16 h = f2b(v);
            ph[n * 32 + c] = h;
            pl[n * 32 + c] = f2b(v - b2f(h));
            s += v * v;
        }
        sq[z * NPTS + n] = s;
    }
}

// ---- conflict-free LDS layout: k-quad-major [kq][row][8], XOR-swizzled ----
__device__ __forceinline__ int lidx(int plane, int row) {
    return ((((plane << 7) | row)) ^ (plane << 1)) << 3;
}
// staged fill split: global->regs (issue early) then regs->LDS (write late) for dbuf pipelining
struct St2 { float4 a, b; };
__device__ __forceinline__ St2 ldStage(const bf16* src, int ld) {
    int t = threadIdx.x; int r = t >> 2, kq = t & 3;
    St2 s;
    s.a = *(const float4*)(src + (size_t)r * ld + kq * 8);
    s.b = *(const float4*)(src + (size_t)(r + 64) * ld + kq * 8);
    return s;
}
__device__ __forceinline__ void stStage(bf16* dst, const St2& s) {
    int t = threadIdx.x; int r = t >> 2, kq = t & 3;
    *(float4*)(dst + lidx(kq, r)) = s.a;
    *(float4*)(dst + lidx(kq, r + 64)) = s.b;
}
// single-shot fill (conv5 keeps the proven 2-barrier structure)
__device__ __forceinline__ void fill128(bf16* dst, const bf16* src, int ld) {
    int t = threadIdx.x;
    int r = t >> 2, kq = t & 3;
    *(float4*)(dst + lidx(kq, r))      = *(const float4*)(src + (size_t)r * ld + kq * 8);
    *(float4*)(dst + lidx(kq, r + 64)) = *(const float4*)(src + (size_t)(r + 64) * ld + kq * 8);
}
// MFMA fragment: sub-tile 'sub' (16 rows of 128), lane l: row=sub*16+(l&15), k=(l>>4)*8..+7
__device__ __forceinline__ v8bf ldf(const bf16* tile, int sub, int l) {
    return *(const v8bf*)(tile + lidx(l >> 4, sub * 16 + (l & 15)));
}

#define TSTRIDE 129   // f32 transpose tile stride (128+1: conflict-free row reads)

// ---------------- fused layer stage A: dist (upper-tri 128x128 tiles) + st ----------------
// 1D grid, XCD-pinned: z = (i>>1)&3, bi = ((i>>3)<<1)|(i&1). Double-buffered K-loop;
// dist mirror write via LDS transpose (coalesced both orientations).
__global__ __launch_bounds__(256) void k_layer_a(const bf16* __restrict__ Xhi, const bf16* __restrict__ Xlo,
                                                 int ld, int Kpad, size_t xstride,
                                                 const bf16* __restrict__ Whi, const bf16* __restrict__ Wlo,
                                                 int O, const float* __restrict__ sqg,
                                                 float* __restrict__ Dg, float* __restrict__ Pg,
                                                 const int* __restrict__ flag) {
    int i = blockIdx.x;
    int z = (i >> 1) & 3;
    int bi = ((i >> 3) << 1) | (i & 1);
    const bf16* Xh = Xhi + (size_t)z * xstride;
    const bf16* Xl = Xlo + (size_t)z * xstride;
    __shared__ alignas(16) char smem[128 * TSTRIDE * 4];   // 66,048 B >= 64 KB staging
    bf16* Ah = (bf16*)smem;                 // [2][4096]
    bf16* Al = (bf16*)(smem + 16384);       // [2][4096]
    bf16* Bh = (bf16*)(smem + 32768);       // [2][4096]
    bf16* Bl = (bf16*)(smem + 49152);       // [2][4096]
    int w = threadIdx.x >> 6, l = threadIdx.x & 63;
    int wr = w >> 1, wc = w & 1;
    int quad = l >> 4, col = l & 15;
    v4f zero = {0.f, 0.f, 0.f, 0.f};
    v4f acc[4][4] = {{zero, zero, zero, zero}, {zero, zero, zero, zero},
                     {zero, zero, zero, zero}, {zero, zero, zero, zero}};

    if (bi < 36) {
        // ---- dist tile: triangular decode over 8x8, bx >= by ----
        int bx = 0;
        while ((((bx + 1) * (bx + 2)) >> 1) <= bi) bx++;
        int by = bi - ((bx * (bx + 1)) >> 1);
        const float* sq = sqg + z * NPTS;
        float* D = Dg + (size_t)z * NPTS * NPTS;
        int n0 = by * 128, m0 = bx * 128;
        const bf16* pAn = Xh + (size_t)n0 * ld;
        const bf16* pAm = Xh + (size_t)m0 * ld;
        const bf16* pLn = Xl + (size_t)n0 * ld;
        const bf16* pLm = Xl + (size_t)m0 * ld;
        St2 sA = ldStage(pAn, ld), sB = ldStage(pAm, ld);
        St2 sC = ldStage(pLn, ld), sD = ldStage(pLm, ld);
        stStage(Ah, sA); stStage(Bh, sB);
        stStage(Al, sC); stStage(Bl, sD);
        __syncthreads();
        int cur = 0;
        for (int k0 = 0; k0 < Kpad; k0 += 32) {
            bool more = (k0 + 32 < Kpad);
            if (more) {
                sA = ldStage(pAn + k0 + 32, ld);
                sB = ldStage(pAm + k0 + 32, ld);
                sC = ldStage(pLn + k0 + 32, ld);
                sD = ldStage(pLm + k0 + 32, ld);
            }
            v8bf ah[4], al[4];
#pragma unroll
            for (int mi = 0; mi < 4; mi++) {
                ah[mi] = ldf(Ah + cur * 4096, wr * 4 + mi, l);
                al[mi] = ldf(Al + cur * 4096, wr * 4 + mi, l);
            }
#pragma unroll
            for (int ni = 0; ni < 4; ni++) {
                v8bf bh = ldf(Bh + cur * 4096, wc * 4 + ni, l);
                v8bf bl = ldf(Bl + cur * 4096, wc * 4 + ni, l);
#pragma unroll
                for (int mi = 0; mi < 4; mi++) {
                    acc[mi][ni] = __builtin_amdgcn_mfma_f32_16x16x32_bf16(ah[mi], bh, acc[mi][ni], 0, 0, 0);
                    acc[mi][ni] = __builtin_amdgcn_mfma_f32_16x16x32_bf16(ah[mi], bl, acc[mi][ni], 0, 0, 0);
                    acc[mi][ni] = __builtin_amdgcn_mfma_f32_16x16x32_bf16(al[mi], bh, acc[mi][ni], 0, 0, 0);
                }
            }
            if (more) {
                stStage(Ah + (cur ^ 1) * 4096, sA); stStage(Bh + (cur ^ 1) * 4096, sB);
                stStage(Al + (cur ^ 1) * 4096, sC); stStage(Bl + (cur ^ 1) * 4096, sD);
            }
            __syncthreads();
            cur ^= 1;
        }
        int rb = n0 + wr * 64 + quad * 4;
        int cb = m0 + wc * 64 + col;
        int rloc = wr * 64 + quad * 4;       // row index within tile
        int cloc = wc * 64 + col;            // col index within tile
        float* Tt = (float*)smem;            // [128][TSTRIDE] f32, aliases dead staging
        float sm[4];
#pragma unroll
        for (int ni = 0; ni < 4; ni++) sm[ni] = sq[cb + ni * 16];
#pragma unroll
        for (int mi = 0; mi < 4; mi++) {
#pragma unroll
            for (int r = 0; r < 4; r++) {
                int row = rb + mi * 16 + r;
                float sn = sq[row];
#pragma unroll
                for (int ni = 0; ni < 4; ni++) {
                    float d = 2.f * acc[mi][ni][r] - sn - sm[ni];
                    D[(size_t)row * NPTS + cb + ni * 16] = d;
                    if (bx != by)
                        Tt[(cloc + ni * 16) * TSTRIDE + rloc + mi * 16 + r] = d;
                }
            }
        }
        if (bx != by) {                      // coalesced transposed write of the mirror
            __syncthreads();
            int t = threadIdx.x;
            int rl = t & 127, ch = t >> 7;
            float* Dm = D + (size_t)m0 * NPTS + n0;
#pragma unroll 4
            for (int it = 0; it < 64; it++) {
                int cl = it * 2 + ch;
                Dm[(size_t)cl * NPTS + rl] = Tt[cl * TSTRIDE + rl];
            }
        }
    } else {
        // ---- st tile: P[point m, weight-row n] over 2O cols ----
        int isf = *flag;
        int nCol = (2 * O) >> 7;
        int s = bi - 36;
        int n0 = (s % nCol) * 128;   // weight-row tile (over 2O)
        int m0 = (s / nCol) * 128;   // point tile (over 1024)
        int N2 = 2 * O;
        float* P = Pg + (size_t)z * NPTS * N2;
        const bf16* pXh = Xh + (size_t)m0 * ld;
        const bf16* pXl = Xl + (size_t)m0 * ld;
        const bf16* pWh = Whi + (size_t)n0 * Kpad;
        const bf16* pWl = Wlo + (size_t)n0 * Kpad;
        St2 sA = ldStage(pXh, ld), sC = ldStage(pXl, ld);
        St2 sB = ldStage(pWh, Kpad), sD;
        if (isf) sD = ldStage(pWl, Kpad);
        stStage(Ah, sA); stStage(Al, sC); stStage(Bh, sB);
        if (isf) stStage(Bl, sD);
        __syncthreads();
        int cur = 0;
        for (int k0 = 0; k0 < Kpad; k0 += 32) {
            bool more = (k0 + 32 < Kpad);
            if (more) {
                sA = ldStage(pXh + k0 + 32, ld);
                sC = ldStage(pXl + k0 + 32, ld);
                sB = ldStage(pWh + k0 + 32, Kpad);
                if (isf) sD = ldStage(pWl + k0 + 32, Kpad);
            }
            v8bf ah[4], al[4];
#pragma unroll
            for (int mi = 0; mi < 4; mi++) {
                ah[mi] = ldf(Ah + cur * 4096, wr * 4 + mi, l);
                al[mi] = ldf(Al + cur * 4096, wr * 4 + mi, l);
            }
#pragma unroll
            for (int ni = 0; ni < 4; ni++) {
                v8bf bh = ldf(Bh + cur * 4096, wc * 4 + ni, l);
#pragma unroll
                for (int mi = 0; mi < 4; mi++) {
                    acc[mi][ni] = __builtin_amdgcn_mfma_f32_16x16x32_bf16(ah[mi], bh, acc[mi][ni], 0, 0, 0);
                    acc[mi][ni] = __builtin_amdgcn_mfma_f32_16x16x32_bf16(al[mi], bh, acc[mi][ni], 0, 0, 0);
                }
                if (isf) {
                    v8bf bl = ldf(Bl + cur * 4096, wc * 4 + ni, l);
#pragma unroll
                    for (int mi = 0; mi < 4; mi++)
                        acc[mi][ni] = __builtin_amdgcn_mfma_f32_16x16x32_bf16(ah[mi], bl, acc[mi][ni], 0, 0, 0);
                }
            }
            if (more) {
                stStage(Ah + (cur ^ 1) * 4096, sA); stStage(Al + (cur ^ 1) * 4096, sC);
                stStage(Bh + (cur ^ 1) * 4096, sB);
                if (isf) stStage(Bl + (cur ^ 1) * 4096, sD);
            }
            __syncthreads();
            cur ^= 1;
        }
        int rb = m0 + wr * 64 + quad * 4;
        int cb = n0 + wc * 64 + col;
#pragma unroll
        for (int mi = 0; mi < 4; mi++)
#pragma unroll
            for (int r = 0; r < 4; r++) {
                int row = rb + mi * 16 + r;
#pragma unroll
                for (int ni = 0; ni < 4; ni++)
                    P[(size_t)row * N2 + cb + ni * 16] = acc[mi][ni][r];
            }
    }
}

// ---- argmax combine via DPP (VALU pipe) ----
template<int CTRL>
__device__ __forceinline__ void dpp_step(float& bv, int& bi) {
    int ov_i = __builtin_amdgcn_update_dpp(__float_as_int(bv), __float_as_int(bv), CTRL, 0xF, 0xF, false);
    int oi   = __builtin_amdgcn_update_dpp(bi, bi, CTRL, 0xF, 0xF, false);
    float ov = __int_as_float(ov_i);
    if (ov > bv || (ov == bv && oi < bi)) { bv = ov; bi = oi; }
}
#define PICK(va, ja, vb, jb, vo, jo) { bool t_ = (vb) > (va); vo = t_ ? (vb) : (va); jo = t_ ? (jb) : (ja); }

// max/min of 20 via balanced triple-trees (exact: max/min fully assoc+comm; max3-fusable)
__device__ __forceinline__ float max20(const float* v) {
    float a0 = fmaxf(fmaxf(v[0], v[1]), v[2]);
    float a1 = fmaxf(fmaxf(v[3], v[4]), v[5]);
    float a2 = fmaxf(fmaxf(v[6], v[7]), v[8]);
    float a3 = fmaxf(fmaxf(v[9], v[10]), v[11]);
    float a4 = fmaxf(fmaxf(v[12], v[13]), v[14]);
    float a5 = fmaxf(fmaxf(v[15], v[16]), v[17]);
    float a6 = fmaxf(v[18], v[19]);
    float b0 = fmaxf(fmaxf(a0, a1), a2);
    float b1 = fmaxf(fmaxf(a3, a4), a5);
    return fmaxf(fmaxf(b0, b1), a6);
}
__device__ __forceinline__ float min20(const float* v) {
    float a0 = fminf(fminf(v[0], v[1]), v[2]);
    float a1 = fminf(fminf(v[3], v[4]), v[5]);
    float a2 = fminf(fminf(v[6], v[7]), v[8]);
    float a3 = fminf(fminf(v[9], v[10]), v[11]);
    float a4 = fminf(fminf(v[12], v[13]), v[14]);
    float a5 = fminf(fminf(v[15], v[16]), v[17]);
    float a6 = fminf(v[18], v[19]);
    float b0 = fminf(fminf(a0, a1), a2);
    float b1 = fminf(fminf(a3, a4), a5);
    return fminf(fminf(b0, b1), a6);
}

// ---------------- fused stage B: top-20 + gather-max, WAVE-PER-ROW end-to-end ----------------
// 1D grid 1024, XCD-pinned: wave q owns row local*4+q. DPP selection; gather with ballot-gated
// fmin path: mn is only consumed when some lane has scl<0 (never at BN init, g=1) -- fast path
// provably never reads mn, slow path unchanged => bit-identical either way.
__global__ __launch_bounds__(256) void k_layer_b(const float* __restrict__ Dg, const float* __restrict__ Pg,
                                                 const void* __restrict__ g, const void* __restrict__ bias,
                                                 int O, bf16* __restrict__ xhOut, bf16* __restrict__ xlOut,
                                                 float* __restrict__ sqOut, int writeSq,
                                                 const int* __restrict__ flag) {
    __shared__ int ids[4][20];
    int isf = *flag;
    int i = blockIdx.x;
    int z = (i >> 1) & 3;
    int local = ((i >> 3) << 1) | (i & 1);
    int tid = threadIdx.x;
    int wq = tid >> 6, l = tid & 63;
    int row = local * 4 + wq;

    // ---- per-wave register-resident top-20 (lane->index map bi = jj*256+l*4+q bijective
    //      over [0,1024), monotone per lane in scan order -> min-index tie-break) ----
    {
        const float* Dr = Dg + (size_t)z * NPTS * NPTS + (size_t)row * NPTS;
        float v[16];
#pragma unroll
        for (int jj = 0; jj < 4; jj++) {
            float4 f4 = *(const float4*)(Dr + jj * 256 + l * 4);
            v[jj * 4 + 0] = f4.x; v[jj * 4 + 1] = f4.y;
            v[jj * 4 + 2] = f4.z; v[jj * 4 + 3] = f4.w;
        }
        float bmv[4]; int bmj[4];
#pragma unroll
        for (int gg = 0; gg < 4; gg++) {
            float a0, a1; int j0, j1;
            PICK(v[4 * gg + 0], 4 * gg + 0, v[4 * gg + 1], 4 * gg + 1, a0, j0);
            PICK(v[4 * gg + 2], 4 * gg + 2, v[4 * gg + 3], 4 * gg + 3, a1, j1);
            PICK(a0, j0, a1, j1, bmv[gg], bmj[gg]);
        }
        for (int s = 0; s < 20; s++) {
            float t0, t1, bv; int s0, s1, bj;
            PICK(bmv[0], bmj[0], bmv[1], bmj[1], t0, s0);
            PICK(bmv[2], bmj[2], bmv[3], bmj[3], t1, s1);
            PICK(t0, s0, t1, s1, bv, bj);
            int bi = (bj >> 2) * 256 + l * 4 + (bj & 3);
            dpp_step<0xB1>(bv, bi);    // quad_perm xor1
            dpp_step<0x4E>(bv, bi);    // quad_perm xor2
            dpp_step<0x124>(bv, bi);   // row_ror:4
            dpp_step<0x128>(bv, bi);   // row_ror:8  -> every lane has its 16-row winner
            dpp_step<0x142>(bv, bi);   // row_bcast15
            dpp_step<0x143>(bv, bi);   // row_bcast31 -> lane63 global
            int bii = __builtin_amdgcn_readlane(bi, 63);   // SGPR broadcast of winner idx
            if (l == 0) ids[wq][s] = bii;
            if (((bii >> 2) & 63) == l) {  // owning lane: evict + rebuild its group
                int ej = (bii >> 8) * 4 + (bii & 3);
                int eg = ej >> 2, ek = ej & 3;
#pragma unroll
                for (int gg = 0; gg < 4; gg++) if (gg == eg) {
#pragma unroll
                    for (int kk = 0; kk < 4; kk++)
                        if (kk == ek) v[4 * gg + kk] = -__builtin_inff();
                    float a0, a1; int j0, j1;
                    PICK(v[4 * gg + 0], 4 * gg + 0, v[4 * gg + 1], 4 * gg + 1, a0, j0);
                    PICK(v[4 * gg + 2], 4 * gg + 2, v[4 * gg + 3], 4 * gg + 3, a1, j1);
                    PICK(a0, j0, a1, j1, bmv[gg], bmj[gg]);
                }
            }
        }
    }

    // ---- gather + max for THIS wave's row (affine/lrelu AFTER max: exact FP-monotone commute) ----
    int N2 = 2 * O;
    const float* P = Pg + (size_t)z * NPTS * N2;
    int offj[20];
#pragma unroll
    for (int j = 0; j < 20; j++)
        offj[j] = __builtin_amdgcn_readfirstlane(ids[wq][j]) * N2;  // SGPR row bases
    int n = row;
    const float* Pn = P + (size_t)n * N2;
    float tot = 0.f;
    int nc = O >> 6;
    for (int c = 0; c < nc; c++) {
        int o = c * 64 + l;
        float scl = ldw(g, o, isf) * BN_SCALE;
        float bb = ldw(bias, o, isf);
        float tv = Pn[O + o] - Pn[o];
        float vv[20];
#pragma unroll
        for (int j = 0; j < 20; j++) vv[j] = P[offj[j] + o];
        float mx = max20(vv);
        float base;
        if (__ballot(scl < 0.f) != 0) {     // wave-uniform; never taken at BN init (g=1)
            float mn = min20(vv);
            base = (scl >= 0.f ? mx : mn) + tv;
        } else {
            base = mx + tv;                 // all scl >= 0: mn provably unused
        }
        float accv = base * scl + bb;
        accv = accv > 0.f ? accv : 0.2f * accv;
        bf16 hi = f2b(accv);
        bf16 lo = f2b(accv - b2f(hi));
        xhOut[(size_t)z * NPTS * 960 + (size_t)n * 960 + o] = hi;
        xlOut[(size_t)z * NPTS * 960 + (size_t)n * 960 + o] = lo;
        if (writeSq) {
            float xv = b2f(hi) + b2f(lo);
            float s2 = xv * xv;
#pragma unroll
            for (int off = 32; off > 0; off >>= 1) s2 += __shfl_down(s2, off);
            if (l == 0) tot += s2;       // ascending chunk order: same serial FP sum as before
        }
    }
    if (writeSq && l == 0) sqOut[z * NPTS + row] = tot;
}

// ---------------- conv5 via MFMA, K-split x6 (chunks of 160) -> f32 partials ----------------
// 1D grid 768, XCD-pinned: z=(i>>1)&3, rest=((i>>3)<<1)|(i&1) in [0,192):
//   ks = rest>>5 (K-chunk), tile = rest&31: m0=(tile>>2)*128, o0=(tile&3)*128
__global__ __launch_bounds__(256) void k_conv5(const bf16* __restrict__ Xhi, const bf16* __restrict__ Xlo,
                                               const bf16* __restrict__ Whi, const bf16* __restrict__ Wlo,
                                               float* __restrict__ P5,
                                               const int* __restrict__ flag) {
    int isf = *flag;
    int i = blockIdx.x;
    int z = (i >> 1) & 3;
    int rest = ((i >> 3) << 1) | (i & 1);
    int ks = rest >> 5;
    int tile = rest & 31;
    int m0 = (tile >> 2) * 128, o0 = (tile & 3) * 128;
    const bf16* Xh = Xhi + (size_t)z * NPTS * 960;
    const bf16* Xl = Xlo + (size_t)z * NPTS * 960;
    __shared__ alignas(16) bf16 Ah[4096], Al[4096], Bh[4096], Bl[4096];
    int w = threadIdx.x >> 6, l = threadIdx.x & 63;
    int wr = w >> 1, wc = w & 1;
    int quad = l >> 4, col = l & 15;
    v4f zero = {0.f, 0.f, 0.f, 0.f};
    v4f acc[4][4] = {{zero, zero, zero, zero}, {zero, zero, zero, zero},
                     {zero, zero, zero, zero}, {zero, zero, zero, zero}};
    int kbeg = ks * 160, kend = kbeg + 160;
    for (int k0 = kbeg; k0 < kend; k0 += 32) {
        __syncthreads();
        fill128(Ah, Xh + (size_t)m0 * 960 + k0, 960);
        fill128(Al, Xl + (size_t)m0 * 960 + k0, 960);
        fill128(Bh, Whi + (size_t)o0 * 960 + k0, 960);
        if (isf) fill128(Bl, Wlo + (size_t)o0 * 960 + k0, 960);
        __syncthreads();
        v8bf ah[4], al[4];
#pragma unroll
        for (int mi = 0; mi < 4; mi++) {
            ah[mi] = ldf(Ah, wr * 4 + mi, l);
            al[mi] = ldf(Al, wr * 4 + mi, l);
        }
#pragma unroll
        for (int ni = 0; ni < 4; ni++) {
            v8bf bh = ldf(Bh, wc * 4 + ni, l);
#pragma unroll
            for (int mi = 0; mi < 4; mi++) {
                acc[mi][ni] = __builtin_amdgcn_mfma_f32_16x16x32_bf16(ah[mi], bh, acc[mi][ni], 0, 0, 0);
                acc[mi][ni] = __builtin_amdgcn_mfma_f32_16x16x32_bf16(al[mi], bh, acc[mi][ni], 0, 0, 0);
            }
            if (isf) {
                v8bf bl = ldf(Bl, wc * 4 + ni, l);
#pragma unroll
                for (int mi = 0; mi < 4; mi++)
                    acc[mi][ni] = __builtin_amdgcn_mfma_f32_16x16x32_bf16(ah[mi], bl, acc[mi][ni], 0, 0, 0);
            }
        }
    }
    // write f32 partial tile (disjoint per (ks,z,tile) -> no atomics)
    float* Pw = P5 + (size_t)ks * CH5 + (size_t)z * NPTS * 512;
    int rb = m0 + wr * 64 + quad * 4;
    int cb = o0 + wc * 64 + col;
#pragma unroll
    for (int mi = 0; mi < 4; mi++)
#pragma unroll
        for (int r = 0; r < 4; r++) {
            int row = rb + mi * 16 + r;
#pragma unroll
            for (int ni = 0; ni < 4; ni++)
                Pw[(size_t)row * 512 + cb + ni * 16] = acc[mi][ni][r];
        }
}

// ---------------- pool5: sum 6 K-chunks + affine + lrelu + max over rows -> pooled ----------------
// 1D grid 512, XCD-pinned: z=(i>>1)&3, rest=((i>>3)<<1)|(i&1) in [0,128):
//   oc=(rest&3)*128 cols, mc=(rest>>2)*32 rows; thread: col=t&127, half=t>>7 (16 rows each)
__global__ __launch_bounds__(256) void k_pool5(const float* __restrict__ P5,
                                               const void* __restrict__ g, const void* __restrict__ bias,
                                               unsigned* __restrict__ pooledU,
                                               const int* __restrict__ flag) {
    __shared__ float red2[128];
    int isf = *flag;
    int i = blockIdx.x;
    int z = (i >> 1) & 3;
    int rest = ((i >> 3) << 1) | (i & 1);
    int oc = (rest & 3) * 128, mc = (rest >> 2) * 32;
    int t = threadIdx.x;
    int c = t & 127, h = t >> 7;
    int o = oc + c;
    float scl = ldw(g, o, isf) * BN_SCALE;
    float bb = ldw(bias, o, isf);
    const float* p0 = P5 + (size_t)z * NPTS * 512 + (size_t)(mc + h * 16) * 512 + o;
    float ym = -__builtin_inff();
    for (int r = 0; r < 16; r++) {
        const float* p = p0 + (size_t)r * 512;
        float s = p[0];
#pragma unroll
        for (int ks = 1; ks < 6; ks++) s += p[(size_t)ks * CH5];
        float v = s * scl + bb;
        v = v > 0.f ? v : 0.2f * v;
        ym = fmaxf(ym, v);
    }
    if (h == 1) red2[c] = ym;
    __syncthreads();
    if (h == 0) {
        float m = fmaxf(ym, red2[c]);
        atomicMax(&pooledU[z * 512 + o], ordf(m));
    }
}

// ---------------- final linear: coalesced wave-per-output ----------------
__global__ void k_final(const unsigned* __restrict__ pooledU, const void* __restrict__ We,
                        void* __restrict__ out, const int* __restrict__ flag) {
    __shared__ float p[512];
    int isf = *flag;
    int b = blockIdx.x >> 2, fb = blockIdx.x & 3;
    int t = threadIdx.x, w = t >> 6, l = t & 63;
    for (int i = t; i < 512; i += 256) p[i] = iordf(pooledU[b * 512 + i]);
    __syncthreads();
    for (int it = 0; it < 16; it++) {
        int f = fb * 64 + w * 16 + it;
        float s = 0.f;
        size_t base = (size_t)f * 512 + l * 8;
#pragma unroll
        for (int j = 0; j < 8; j++) s += p[l * 8 + j] * ldw(We, base + j, isf);
#pragma unroll
        for (int off = 32; off > 0; off >>= 1) s += __shfl_down(s, off);
        if (l == 0) {
            if (isf) ((float*)out)[b * 256 + f] = s;
            else     ((bf16*)out)[b * 256 + f] = f2b(s);
        }
    }
}

extern "C" void kernel_launch(void* const* d_in, const int* in_sizes, int n_in,
                              void* d_out, int out_size, void* d_ws, size_t ws_size,
                              hipStream_t stream) {
    const void* x  = d_in[0];
    const void* Wl[4] = { d_in[1], d_in[4], d_in[7], d_in[10] };
    const void* gl[4] = { d_in[2], d_in[5], d_in[8], d_in[11] };
    const void* bl[4] = { d_in[3], d_in[6], d_in[9], d_in[12] };
    const void* W5 = d_in[13];
    const void* g5 = d_in[14];
    const void* b5 = d_in[15];
    const void* We = d_in[16];

    // workspace layout (bytes), ~103.9 MB total
    char* base = (char*)d_ws;
    bf16*     xc_hi   = (bf16*)(base);                  // 7,864,320
    bf16*     xc_lo   = (bf16*)(base + 7864320);        // 7,864,320
    bf16*     xpadh   = (bf16*)(base + 15728640);       // 262,144
    bf16*     xpadl   = (bf16*)(base + 15990784);       // 262,144
    float*    Dbuf    = (float*)(base + 16252928);      // 16,777,216
    float*    Pbuf    = (float*)(base + 33030144);      // 16,777,216
    bf16*     Whi     = (bf16*)(base + 49807360);       // 1,679,360
    bf16*     Wlo     = (bf16*)(base + 51486720);       // 1,679,360
    unsigned* pooledU = (unsigned*)(base + 53493760);   // 8,192
    float*    sq      = (float*)(base + 53501952);      // 16,384
    int*      flag    = (int*)(base + 53518336);        // 4
    float*    P5      = (float*)(base + 53520384);      // 50,331,648 (6 x 8 MB conv5 partials)

    const int Kpad[4]   = { 32, 64, 128, 256 };
    const int Os[4]     = { 64, 128, 256, 512 };
    const int Woff[5]   = { 0, 4096, 20480, 86016, 348160 };
    const int colIn[4]  = { 0, 0, 64, 192 };
    const int colOut[4] = { 0, 64, 192, 448 };

    k_prep<<<3296, 256, 0, stream>>>(Wl[0], Wl[1], Wl[2], Wl[3], W5, x,
                                     Whi, Wlo, xpadh, xpadl, sq, flag, pooledU);

    for (int l = 0; l < 4; l++) {
        int O = Os[l];
        int nCol = (2 * O) >> 7;
        int nBlk = 36 + 8 * nCol;  // 44/52/68/100 -> *4 divisible by 8 for XCD decode
        const bf16* Xh = (l == 0) ? xpadh : (xc_hi + colIn[l]);
        const bf16* Xl = (l == 0) ? xpadl : (xc_lo + colIn[l]);
        int ld = (l == 0) ? 32 : 960;
        size_t xstr = (l == 0) ? (size_t)NPTS * 32 : (size_t)NPTS * 960;
        k_layer_a<<<nBlk * NB, 256, 0, stream>>>(
            Xh, Xl, ld, Kpad[l], xstr, Whi + Woff[l], Wlo + Woff[l], O, sq, Dbuf, Pbuf, flag);
        k_layer_b<<<NPTS * NB / 4, 256, 0, stream>>>(
            Dbuf, Pbuf, gl[l], bl[l], O, xc_hi + colOut[l], xc_lo + colOut[l], sq, l < 3, flag);
    }
    k_conv5<<<768, 256, 0, stream>>>(xc_hi, xc_lo, Whi + Woff[4], Wlo + Woff[4], P5, flag);
    k_pool5<<<512, 256, 0, stream>>>(P5, g5, b5, pooledU, flag);
    k_final<<<16, 256, 0, stream>>>(pooledU, We, d_out, flag);
}

// Round 18
// 282.885 us; speedup vs baseline: 1.6071x; 1.0431x over previous
//
#include <hip/hip_runtime.h>
#include <hip/hip_bf16.h>
#include <math.h>

typedef __hip_bfloat16 bf16;
typedef __bf16 v8bf __attribute__((ext_vector_type(8)));
typedef float v4f __attribute__((ext_vector_type(4)));

#define BN_SCALE 0.9999950000374997f
#define NPTS 1024
#define NB 4
#define CH5 ((size_t)4 * 1024 * 512)   // conv5 partial-chunk stride (floats)

__device__ __forceinline__ float b2f(bf16 v) { return __bfloat162float(v); }
__device__ __forceinline__ bf16 f2b(float v) { return __float2bfloat16(v); }
__device__ __forceinline__ float ldw(const void* p, size_t i, int isf) {
    return isf ? ((const float*)p)[i] : b2f(((const bf16*)p)[i]);
}
__device__ __forceinline__ unsigned ordf(float f) {
    unsigned u = __float_as_uint(f);
    return (u & 0x80000000u) ? ~u : (u | 0x80000000u);
}
__device__ __forceinline__ float iordf(unsigned u) {
    return (u & 0x80000000u) ? __uint_as_float(u ^ 0x80000000u) : __uint_as_float(~u);
}

// per-block dtype detect from first 512 shorts of x (fp32 ~113/256 implausible, bf16 ~0)
__device__ __forceinline__ int detect_isf(const void* xraw, int* cnt) {
    const unsigned short* u = (const unsigned short*)xraw;
    int t = threadIdx.x, c = 0;
    for (int i = t; i < 512; i += 256) {
        unsigned short v = u[i];
        int e = (v >> 7) & 0xFF;
        int m = v & 0x7F;
        if (e == 0xFF || e >= 141 || (e == 0 && m != 0)) c++;
    }
    cnt[t] = c;
    __syncthreads();
    for (int off = 128; off > 0; off >>= 1) {
        if (t < off) cnt[t] += cnt[t + off];
        __syncthreads();
    }
    int isf = (cnt[0] > 30) ? 1 : 0;
    __syncthreads();
    return isf;
}

// ---------------- fused prep: dtype flag + pooled init + weight splits + x pad + sq ----------------
__global__ void k_prep(const void* __restrict__ W1, const void* __restrict__ W2,
                       const void* __restrict__ W3, const void* __restrict__ W4,
                       const void* __restrict__ W5, const void* __restrict__ x,
                       bf16* __restrict__ Whi, bf16* __restrict__ Wlo,
                       bf16* __restrict__ xph, bf16* __restrict__ xpl, float* __restrict__ sq,
                       int* __restrict__ flag, unsigned* __restrict__ pooledU) {
    __shared__ int cnt[256];
    int isf = detect_isf(x, cnt);
    if (blockIdx.x == 0) {
        if (threadIdx.x == 0) *flag = isf;
        for (int i = threadIdx.x; i < 2048; i += 256) pooledU[i] = 0u;  // 0 < ordf(any finite)
    }
    int idx = blockIdx.x * 256 + threadIdx.x;
    if (idx < 839680) {
        const void* src; int C, O, Kpad, two, local;
        if (idx < 4096)        { src = W1; C = 3;   O = 64;  Kpad = 32;  two = 1; local = idx; }
        else if (idx < 20480)  { src = W2; C = 64;  O = 128; Kpad = 64;  two = 1; local = idx - 4096; }
        else if (idx < 86016)  { src = W3; C = 128; O = 256; Kpad = 128; two = 1; local = idx - 20480; }
        else if (idx < 348160) { src = W4; C = 256; O = 512; Kpad = 256; two = 1; local = idx - 86016; }
        else                   { src = W5; C = 960; O = 512; Kpad = 960; two = 0; local = idx - 348160; }
        int r = local / Kpad, c = local % Kpad;
        float wv = 0.f;
        if (c < C) {
            size_t off;
            if (two) off = (r < O) ? (size_t)r * 2 * C + c : (size_t)(r - O) * 2 * C + C + c;
            else     off = (size_t)r * C + c;
            wv = ldw(src, off, isf);
        }
        bf16 h = f2b(wv);
        Whi[idx] = h;
        Wlo[idx] = f2b(wv - b2f(h));
    } else if (idx < 843776) {
        int p = idx - 839680;       // point index: z*1024 + n
        int z = p >> 10, n = p & 1023;
        bf16* ph = xph + (size_t)z * NPTS * 32;
        bf16* pl = xpl + (size_t)z * NPTS * 32;
        float s = 0.f;
        for (int c = 0; c < 32; c++) {
            float v = (c < 3) ? ldw(x, (size_t)z * NPTS * 3 + n * 3 + c, isf) : 0.f;
            bf16 h = f2b(v);
            ph[n * 32 + c] = h;
            pl[n * 32 + c] = f2b(v - b2f(h));
            s += v * v;
        }
        sq[z * NPTS + n] = s;
    }
}

// ---- conflict-free LDS layout: k-quad-major [kq][row][8], XOR-swizzled ----
__device__ __forceinline__ int lidx(int plane, int row) {
    return ((((plane << 7) | row)) ^ (plane << 1)) << 3;
}
// staged fill split: global->regs (issue early) then regs->LDS (write late) for dbuf pipelining
struct St2 { float4 a, b; };
__device__ __forceinline__ St2 ldStage(const bf16* src, int ld) {
    int t = threadIdx.x; int r = t >> 2, kq = t & 3;
    St2 s;
    s.a = *(const float4*)(src + (size_t)r * ld + kq * 8);
    s.b = *(const float4*)(src + (size_t)(r + 64) * ld + kq * 8);
    return s;
}
__device__ __forceinline__ void stStage(bf16* dst, const St2& s) {
    int t = threadIdx.x; int r = t >> 2, kq = t & 3;
    *(float4*)(dst + lidx(kq, r)) = s.a;
    *(float4*)(dst + lidx(kq, r + 64)) = s.b;
}
// single-shot fill (conv5 keeps the proven 2-barrier structure)
__device__ __forceinline__ void fill128(bf16* dst, const bf16* src, int ld) {
    int t = threadIdx.x;
    int r = t >> 2, kq = t & 3;
    *(float4*)(dst + lidx(kq, r))      = *(const float4*)(src + (size_t)r * ld + kq * 8);
    *(float4*)(dst + lidx(kq, r + 64)) = *(const float4*)(src + (size_t)(r + 64) * ld + kq * 8);
}
// MFMA fragment: sub-tile 'sub' (16 rows of 128), lane l: row=sub*16+(l&15), k=(l>>4)*8..+7
__device__ __forceinline__ v8bf ldf(const bf16* tile, int sub, int l) {
    return *(const v8bf*)(tile + lidx(l >> 4, sub * 16 + (l & 15)));
}

#define TSTRIDE 129   // f32 transpose tile stride (128+1: conflict-free row reads)

// ---------------- fused layer stage A: dist (upper-tri 128x128 tiles) + st ----------------
// 1D grid, XCD-pinned: z = (i>>1)&3, bi = ((i>>3)<<1)|(i&1). Double-buffered K-loop;
// dist mirror write via LDS transpose (coalesced both orientations).
__global__ __launch_bounds__(256) void k_layer_a(const bf16* __restrict__ Xhi, const bf16* __restrict__ Xlo,
                                                 int ld, int Kpad, size_t xstride,
                                                 const bf16* __restrict__ Whi, const bf16* __restrict__ Wlo,
                                                 int O, const float* __restrict__ sqg,
                                                 float* __restrict__ Dg, float* __restrict__ Pg,
                                                 const int* __restrict__ flag) {
    int i = blockIdx.x;
    int z = (i >> 1) & 3;
    int bi = ((i >> 3) << 1) | (i & 1);
    const bf16* Xh = Xhi + (size_t)z * xstride;
    const bf16* Xl = Xlo + (size_t)z * xstride;
    __shared__ alignas(16) char smem[128 * TSTRIDE * 4];   // 66,048 B >= 64 KB staging
    bf16* Ah = (bf16*)smem;                 // [2][4096]
    bf16* Al = (bf16*)(smem + 16384);       // [2][4096]
    bf16* Bh = (bf16*)(smem + 32768);       // [2][4096]
    bf16* Bl = (bf16*)(smem + 49152);       // [2][4096]
    int w = threadIdx.x >> 6, l = threadIdx.x & 63;
    int wr = w >> 1, wc = w & 1;
    int quad = l >> 4, col = l & 15;
    v4f zero = {0.f, 0.f, 0.f, 0.f};
    v4f acc[4][4] = {{zero, zero, zero, zero}, {zero, zero, zero, zero},
                     {zero, zero, zero, zero}, {zero, zero, zero, zero}};

    if (bi < 36) {
        // ---- dist tile: triangular decode over 8x8, bx >= by ----
        int bx = 0;
        while ((((bx + 1) * (bx + 2)) >> 1) <= bi) bx++;
        int by = bi - ((bx * (bx + 1)) >> 1);
        const float* sq = sqg + z * NPTS;
        float* D = Dg + (size_t)z * NPTS * NPTS;
        int n0 = by * 128, m0 = bx * 128;
        const bf16* pAn = Xh + (size_t)n0 * ld;
        const bf16* pAm = Xh + (size_t)m0 * ld;
        const bf16* pLn = Xl + (size_t)n0 * ld;
        const bf16* pLm = Xl + (size_t)m0 * ld;
        St2 sA = ldStage(pAn, ld), sB = ldStage(pAm, ld);
        St2 sC = ldStage(pLn, ld), sD = ldStage(pLm, ld);
        stStage(Ah, sA); stStage(Bh, sB);
        stStage(Al, sC); stStage(Bl, sD);
        __syncthreads();
        int cur = 0;
        for (int k0 = 0; k0 < Kpad; k0 += 32) {
            bool more = (k0 + 32 < Kpad);
            if (more) {
                sA = ldStage(pAn + k0 + 32, ld);
                sB = ldStage(pAm + k0 + 32, ld);
                sC = ldStage(pLn + k0 + 32, ld);
                sD = ldStage(pLm + k0 + 32, ld);
            }
            v8bf ah[4], al[4];
#pragma unroll
            for (int mi = 0; mi < 4; mi++) {
                ah[mi] = ldf(Ah + cur * 4096, wr * 4 + mi, l);
                al[mi] = ldf(Al + cur * 4096, wr * 4 + mi, l);
            }
#pragma unroll
            for (int ni = 0; ni < 4; ni++) {
                v8bf bh = ldf(Bh + cur * 4096, wc * 4 + ni, l);
                v8bf bl = ldf(Bl + cur * 4096, wc * 4 + ni, l);
#pragma unroll
                for (int mi = 0; mi < 4; mi++) {
                    acc[mi][ni] = __builtin_amdgcn_mfma_f32_16x16x32_bf16(ah[mi], bh, acc[mi][ni], 0, 0, 0);
                    acc[mi][ni] = __builtin_amdgcn_mfma_f32_16x16x32_bf16(ah[mi], bl, acc[mi][ni], 0, 0, 0);
                    acc[mi][ni] = __builtin_amdgcn_mfma_f32_16x16x32_bf16(al[mi], bh, acc[mi][ni], 0, 0, 0);
                }
            }
            if (more) {
                stStage(Ah + (cur ^ 1) * 4096, sA); stStage(Bh + (cur ^ 1) * 4096, sB);
                stStage(Al + (cur ^ 1) * 4096, sC); stStage(Bl + (cur ^ 1) * 4096, sD);
            }
            __syncthreads();
            cur ^= 1;
        }
        int rb = n0 + wr * 64 + quad * 4;
        int cb = m0 + wc * 64 + col;
        int rloc = wr * 64 + quad * 4;       // row index within tile
        int cloc = wc * 64 + col;            // col index within tile
        float* Tt = (float*)smem;            // [128][TSTRIDE] f32, aliases dead staging
        float sm[4];
#pragma unroll
        for (int ni = 0; ni < 4; ni++) sm[ni] = sq[cb + ni * 16];
#pragma unroll
        for (int mi = 0; mi < 4; mi++) {
#pragma unroll
            for (int r = 0; r < 4; r++) {
                int row = rb + mi * 16 + r;
                float sn = sq[row];
#pragma unroll
                for (int ni = 0; ni < 4; ni++) {
                    float d = 2.f * acc[mi][ni][r] - sn - sm[ni];
                    D[(size_t)row * NPTS + cb + ni * 16] = d;
                    if (bx != by)
                        Tt[(cloc + ni * 16) * TSTRIDE + rloc + mi * 16 + r] = d;
                }
            }
        }
        if (bx != by) {                      // coalesced transposed write of the mirror
            __syncthreads();
            int t = threadIdx.x;
            int rl = t & 127, ch = t >> 7;
            float* Dm = D + (size_t)m0 * NPTS + n0;
#pragma unroll 4
            for (int it = 0; it < 64; it++) {
                int cl = it * 2 + ch;
                Dm[(size_t)cl * NPTS + rl] = Tt[cl * TSTRIDE + rl];
            }
        }
    } else {
        // ---- st tile: P[point m, weight-row n] over 2O cols ----
        int isf = *flag;
        int nCol = (2 * O) >> 7;
        int s = bi - 36;
        int n0 = (s % nCol) * 128;   // weight-row tile (over 2O)
        int m0 = (s / nCol) * 128;   // point tile (over 1024)
        int N2 = 2 * O;
        float* P = Pg + (size_t)z * NPTS * N2;
        const bf16* pXh = Xh + (size_t)m0 * ld;
        const bf16* pXl = Xl + (size_t)m0 * ld;
        const bf16* pWh = Whi + (size_t)n0 * Kpad;
        const bf16* pWl = Wlo + (size_t)n0 * Kpad;
        St2 sA = ldStage(pXh, ld), sC = ldStage(pXl, ld);
        St2 sB = ldStage(pWh, Kpad), sD;
        if (isf) sD = ldStage(pWl, Kpad);
        stStage(Ah, sA); stStage(Al, sC); stStage(Bh, sB);
        if (isf) stStage(Bl, sD);
        __syncthreads();
        int cur = 0;
        for (int k0 = 0; k0 < Kpad; k0 += 32) {
            bool more = (k0 + 32 < Kpad);
            if (more) {
                sA = ldStage(pXh + k0 + 32, ld);
                sC = ldStage(pXl + k0 + 32, ld);
                sB = ldStage(pWh + k0 + 32, Kpad);
                if (isf) sD = ldStage(pWl + k0 + 32, Kpad);
            }
            v8bf ah[4], al[4];
#pragma unroll
            for (int mi = 0; mi < 4; mi++) {
                ah[mi] = ldf(Ah + cur * 4096, wr * 4 + mi, l);
                al[mi] = ldf(Al + cur * 4096, wr * 4 + mi, l);
            }
#pragma unroll
            for (int ni = 0; ni < 4; ni++) {
                v8bf bh = ldf(Bh + cur * 4096, wc * 4 + ni, l);
#pragma unroll
                for (int mi = 0; mi < 4; mi++) {
                    acc[mi][ni] = __builtin_amdgcn_mfma_f32_16x16x32_bf16(ah[mi], bh, acc[mi][ni], 0, 0, 0);
                    acc[mi][ni] = __builtin_amdgcn_mfma_f32_16x16x32_bf16(al[mi], bh, acc[mi][ni], 0, 0, 0);
                }
                if (isf) {
                    v8bf bl = ldf(Bl + cur * 4096, wc * 4 + ni, l);
#pragma unroll
                    for (int mi = 0; mi < 4; mi++)
                        acc[mi][ni] = __builtin_amdgcn_mfma_f32_16x16x32_bf16(ah[mi], bl, acc[mi][ni], 0, 0, 0);
                }
            }
            if (more) {
                stStage(Ah + (cur ^ 1) * 4096, sA); stStage(Al + (cur ^ 1) * 4096, sC);
                stStage(Bh + (cur ^ 1) * 4096, sB);
                if (isf) stStage(Bl + (cur ^ 1) * 4096, sD);
            }
            __syncthreads();
            cur ^= 1;
        }
        int rb = m0 + wr * 64 + quad * 4;
        int cb = n0 + wc * 64 + col;
#pragma unroll
        for (int mi = 0; mi < 4; mi++)
#pragma unroll
            for (int r = 0; r < 4; r++) {
                int row = rb + mi * 16 + r;
#pragma unroll
                for (int ni = 0; ni < 4; ni++)
                    P[(size_t)row * N2 + cb + ni * 16] = acc[mi][ni][r];
            }
    }
}

// ---- DPP wave reduce steps (VALU pipe): val-only fmax, idx-only min_u32 ----
template<int CTRL>
__device__ __forceinline__ void dpp_fmax(float& bv) {
    int ov = __builtin_amdgcn_update_dpp(__float_as_int(bv), __float_as_int(bv), CTRL, 0xF, 0xF, false);
    bv = fmaxf(bv, __int_as_float(ov));
}
template<int CTRL>
__device__ __forceinline__ void dpp_umin(unsigned& m) {
    unsigned om = (unsigned)__builtin_amdgcn_update_dpp((int)m, (int)m, CTRL, 0xF, 0xF, false);
    m = m < om ? m : om;
}
#define PICK(va, ja, vb, jb, vo, jo) { bool t_ = (vb) > (va); vo = t_ ? (vb) : (va); jo = t_ ? (jb) : (ja); }

// max/min of 20 via balanced triple-trees (exact: max/min fully assoc+comm; max3-fusable)
__device__ __forceinline__ float max20(const float* v) {
    float a0 = fmaxf(fmaxf(v[0], v[1]), v[2]);
    float a1 = fmaxf(fmaxf(v[3], v[4]), v[5]);
    float a2 = fmaxf(fmaxf(v[6], v[7]), v[8]);
    float a3 = fmaxf(fmaxf(v[9], v[10]), v[11]);
    float a4 = fmaxf(fmaxf(v[12], v[13]), v[14]);
    float a5 = fmaxf(fmaxf(v[15], v[16]), v[17]);
    float a6 = fmaxf(v[18], v[19]);
    float b0 = fmaxf(fmaxf(a0, a1), a2);
    float b1 = fmaxf(fmaxf(a3, a4), a5);
    return fmaxf(fmaxf(b0, b1), a6);
}
__device__ __forceinline__ float min20(const float* v) {
    float a0 = fminf(fminf(v[0], v[1]), v[2]);
    float a1 = fminf(fminf(v[3], v[4]), v[5]);
    float a2 = fminf(fminf(v[6], v[7]), v[8]);
    float a3 = fminf(fminf(v[9], v[10]), v[11]);
    float a4 = fminf(fminf(v[12], v[13]), v[14]);
    float a5 = fminf(fminf(v[15], v[16]), v[17]);
    float a6 = fminf(v[18], v[19]);
    float b0 = fminf(fminf(a0, a1), a2);
    float b1 = fminf(fminf(a3, a4), a5);
    return fminf(fminf(b0, b1), a6);
}

// ---------------- fused stage B: top-20 + gather-max, WAVE-PER-ROW end-to-end ----------------
// Selection with PERSISTENT per-lane candidates (tree recomputed only by the evicted owner) and
// a SPLIT butterfly: phase1 val-only fmax (6x2 inst) -> gmax; phase2 idx-only min_u32 among
// gmax-holders -> global (max, min-idx) winner. Exact: fmax propagates the exact max; candidate
// idx is lane-unique; u32 min over global indices (<2^31) picks the same unique winner as the
// combined total-order reduce. ids bit-identical to prior rounds.
__global__ __launch_bounds__(256) void k_layer_b(const float* __restrict__ Dg, const float* __restrict__ Pg,
                                                 const void* __restrict__ g, const void* __restrict__ bias,
                                                 int O, bf16* __restrict__ xhOut, bf16* __restrict__ xlOut,
                                                 float* __restrict__ sqOut, int writeSq,
                                                 const int* __restrict__ flag) {
    __shared__ int ids[4][20];
    int isf = *flag;
    int i = blockIdx.x;
    int z = (i >> 1) & 3;
    int local = ((i >> 3) << 1) | (i & 1);
    int tid = threadIdx.x;
    int wq = tid >> 6, l = tid & 63;
    int row = local * 4 + wq;

    // ---- per-wave register-resident top-20 (lane->index map bi = jj*256+l*4+q bijective
    //      over [0,1024), monotone per lane in scan order -> min-index tie-break) ----
    {
        const float* Dr = Dg + (size_t)z * NPTS * NPTS + (size_t)row * NPTS;
        float v[16];
#pragma unroll
        for (int jj = 0; jj < 4; jj++) {
            float4 f4 = *(const float4*)(Dr + jj * 256 + l * 4);
            v[jj * 4 + 0] = f4.x; v[jj * 4 + 1] = f4.y;
            v[jj * 4 + 2] = f4.z; v[jj * 4 + 3] = f4.w;
        }
        float bmv[4]; int bmj[4];
#pragma unroll
        for (int gg = 0; gg < 4; gg++) {
            float a0, a1; int j0, j1;
            PICK(v[4 * gg + 0], 4 * gg + 0, v[4 * gg + 1], 4 * gg + 1, a0, j0);
            PICK(v[4 * gg + 2], 4 * gg + 2, v[4 * gg + 3], 4 * gg + 3, a1, j1);
            PICK(a0, j0, a1, j1, bmv[gg], bmj[gg]);
        }
        // persistent lane candidate (candv, candi): tree over group winners, global idx map
        float candv; int candj, candi;
        {
            float t0, t1; int s0, s1;
            PICK(bmv[0], bmj[0], bmv[1], bmj[1], t0, s0);
            PICK(bmv[2], bmj[2], bmv[3], bmj[3], t1, s1);
            PICK(t0, s0, t1, s1, candv, candj);
            candi = (candj >> 2) * 256 + l * 4 + (candj & 3);
        }
        for (int s = 0; s < 20; s++) {
            // phase 1: wave max of candidate values (val-only butterfly)
            float bv = candv;
            dpp_fmax<0xB1>(bv);    // quad_perm xor1
            dpp_fmax<0x4E>(bv);    // quad_perm xor2
            dpp_fmax<0x124>(bv);   // row_ror:4
            dpp_fmax<0x128>(bv);   // row_ror:8
            dpp_fmax<0x142>(bv);   // row_bcast15
            dpp_fmax<0x143>(bv);   // row_bcast31 -> lane63 = global max
            float gmax = __int_as_float(__builtin_amdgcn_readlane(__float_as_int(bv), 63));
            // phase 2: min global idx among lanes whose candidate holds gmax
            unsigned mi = (candv == gmax) ? (unsigned)candi : 0xFFFFFFFFu;
            dpp_umin<0xB1>(mi);
            dpp_umin<0x4E>(mi);
            dpp_umin<0x124>(mi);
            dpp_umin<0x128>(mi);
            dpp_umin<0x142>(mi);
            dpp_umin<0x143>(mi);   // lane63 = min idx
            int bii = __builtin_amdgcn_readlane((int)mi, 63);   // SGPR broadcast
            if (l == 0) ids[wq][s] = bii;
            if (candi == bii) {    // unique owner (candi lane-unique): evict + rebuild
                int ej = (bii >> 8) * 4 + (bii & 3);
                int eg = ej >> 2, ek = ej & 3;
#pragma unroll
                for (int gg = 0; gg < 4; gg++) if (gg == eg) {
#pragma unroll
                    for (int kk = 0; kk < 4; kk++)
                        if (kk == ek) v[4 * gg + kk] = -__builtin_inff();
                    float a0, a1; int j0, j1;
                    PICK(v[4 * gg + 0], 4 * gg + 0, v[4 * gg + 1], 4 * gg + 1, a0, j0);
                    PICK(v[4 * gg + 2], 4 * gg + 2, v[4 * gg + 3], 4 * gg + 3, a1, j1);
                    PICK(a0, j0, a1, j1, bmv[gg], bmj[gg]);
                }
                float t0, t1; int s0, s1;
                PICK(bmv[0], bmj[0], bmv[1], bmj[1], t0, s0);
                PICK(bmv[2], bmj[2], bmv[3], bmj[3], t1, s1);
                PICK(t0, s0, t1, s1, candv, candj);
                candi = (candj >> 2) * 256 + l * 4 + (candj & 3);
            }
        }
    }

    // ---- gather + max for THIS wave's row (affine/lrelu AFTER max: exact FP-monotone commute) ----
    int N2 = 2 * O;
    const float* P = Pg + (size_t)z * NPTS * N2;
    int offj[20];
#pragma unroll
    for (int j = 0; j < 20; j++)
        offj[j] = __builtin_amdgcn_readfirstlane(ids[wq][j]) * N2;  // SGPR row bases
    int n = row;
    const float* Pn = P + (size_t)n * N2;
    float tot = 0.f;
    int nc = O >> 6;
    for (int c = 0; c < nc; c++) {
        int o = c * 64 + l;
        float scl = ldw(g, o, isf) * BN_SCALE;
        float bb = ldw(bias, o, isf);
        float tv = Pn[O + o] - Pn[o];
        float vv[20];
#pragma unroll
        for (int j = 0; j < 20; j++) vv[j] = P[offj[j] + o];
        float mx = max20(vv);
        float base;
        if (__ballot(scl < 0.f) != 0) {     // wave-uniform; never taken at BN init (g=1)
            float mn = min20(vv);
            base = (scl >= 0.f ? mx : mn) + tv;
        } else {
            base = mx + tv;                 // all scl >= 0: mn provably unused
        }
        float accv = base * scl + bb;
        accv = accv > 0.f ? accv : 0.2f * accv;
        bf16 hi = f2b(accv);
        bf16 lo = f2b(accv - b2f(hi));
        xhOut[(size_t)z * NPTS * 960 + (size_t)n * 960 + o] = hi;
        xlOut[(size_t)z * NPTS * 960 + (size_t)n * 960 + o] = lo;
        if (writeSq) {
            float xv = b2f(hi) + b2f(lo);
            float s2 = xv * xv;
#pragma unroll
            for (int off = 32; off > 0; off >>= 1) s2 += __shfl_down(s2, off);
            if (l == 0) tot += s2;       // ascending chunk order: same serial FP sum as before
        }
    }
    if (writeSq && l == 0) sqOut[z * NPTS + row] = tot;
}

// ---------------- conv5 via MFMA, K-split x6 (chunks of 160) -> f32 partials ----------------
// 1D grid 768, XCD-pinned: z=(i>>1)&3, rest=((i>>3)<<1)|(i&1) in [0,192):
//   ks = rest>>5 (K-chunk), tile = rest&31: m0=(tile>>2)*128, o0=(tile&3)*128
__global__ __launch_bounds__(256) void k_conv5(const bf16* __restrict__ Xhi, const bf16* __restrict__ Xlo,
                                               const bf16* __restrict__ Whi, const bf16* __restrict__ Wlo,
                                               float* __restrict__ P5,
                                               const int* __restrict__ flag) {
    int isf = *flag;
    int i = blockIdx.x;
    int z = (i >> 1) & 3;
    int rest = ((i >> 3) << 1) | (i & 1);
    int ks = rest >> 5;
    int tile = rest & 31;
    int m0 = (tile >> 2) * 128, o0 = (tile & 3) * 128;
    const bf16* Xh = Xhi + (size_t)z * NPTS * 960;
    const bf16* Xl = Xlo + (size_t)z * NPTS * 960;
    __shared__ alignas(16) bf16 Ah[4096], Al[4096], Bh[4096], Bl[4096];
    int w = threadIdx.x >> 6, l = threadIdx.x & 63;
    int wr = w >> 1, wc = w & 1;
    int quad = l >> 4, col = l & 15;
    v4f zero = {0.f, 0.f, 0.f, 0.f};
    v4f acc[4][4] = {{zero, zero, zero, zero}, {zero, zero, zero, zero},
                     {zero, zero, zero, zero}, {zero, zero, zero, zero}};
    int kbeg = ks * 160, kend = kbeg + 160;
    for (int k0 = kbeg; k0 < kend; k0 += 32) {
        __syncthreads();
        fill128(Ah, Xh + (size_t)m0 * 960 + k0, 960);
        fill128(Al, Xl + (size_t)m0 * 960 + k0, 960);
        fill128(Bh, Whi + (size_t)o0 * 960 + k0, 960);
        if (isf) fill128(Bl, Wlo + (size_t)o0 * 960 + k0, 960);
        __syncthreads();
        v8bf ah[4], al[4];
#pragma unroll
        for (int mi = 0; mi < 4; mi++) {
            ah[mi] = ldf(Ah, wr * 4 + mi, l);
            al[mi] = ldf(Al, wr * 4 + mi, l);
        }
#pragma unroll
        for (int ni = 0; ni < 4; ni++) {
            v8bf bh = ldf(Bh, wc * 4 + ni, l);
#pragma unroll
            for (int mi = 0; mi < 4; mi++) {
                acc[mi][ni] = __builtin_amdgcn_mfma_f32_16x16x32_bf16(ah[mi], bh, acc[mi][ni], 0, 0, 0);
                acc[mi][ni] = __builtin_amdgcn_mfma_f32_16x16x32_bf16(al[mi], bh, acc[mi][ni], 0, 0, 0);
            }
            if (isf) {
                v8bf bl = ldf(Bl, wc * 4 + ni, l);
#pragma unroll
                for (int mi = 0; mi < 4; mi++)
                    acc[mi][ni] = __builtin_amdgcn_mfma_f32_16x16x32_bf16(ah[mi], bl, acc[mi][ni], 0, 0, 0);
            }
        }
    }
    // write f32 partial tile (disjoint per (ks,z,tile) -> no atomics)
    float* Pw = P5 + (size_t)ks * CH5 + (size_t)z * NPTS * 512;
    int rb = m0 + wr * 64 + quad * 4;
    int cb = o0 + wc * 64 + col;
#pragma unroll
    for (int mi = 0; mi < 4; mi++)
#pragma unroll
        for (int r = 0; r < 4; r++) {
            int row = rb + mi * 16 + r;
#pragma unroll
            for (int ni = 0; ni < 4; ni++)
                Pw[(size_t)row * 512 + cb + ni * 16] = acc[mi][ni][r];
        }
}

// ---------------- pool5: sum 6 K-chunks + affine + lrelu + max over rows -> pooled ----------------
// 1D grid 512, XCD-pinned: z=(i>>1)&3, rest=((i>>3)<<1)|(i&1) in [0,128):
//   oc=(rest&3)*128 cols, mc=(rest>>2)*32 rows; thread: col=t&127, half=t>>7 (16 rows each)
__global__ __launch_bounds__(256) void k_pool5(const float* __restrict__ P5,
                                               const void* __restrict__ g, const void* __restrict__ bias,
                                               unsigned* __restrict__ pooledU,
                                               const int* __restrict__ flag) {
    __shared__ float red2[128];
    int isf = *flag;
    int i = blockIdx.x;
    int z = (i >> 1) & 3;
    int rest = ((i >> 3) << 1) | (i & 1);
    int oc = (rest & 3) * 128, mc = (rest >> 2) * 32;
    int t = threadIdx.x;
    int c = t & 127, h = t >> 7;
    int o = oc + c;
    float scl = ldw(g, o, isf) * BN_SCALE;
    float bb = ldw(bias, o, isf);
    const float* p0 = P5 + (size_t)z * NPTS * 512 + (size_t)(mc + h * 16) * 512 + o;
    float ym = -__builtin_inff();
    for (int r = 0; r < 16; r++) {
        const float* p = p0 + (size_t)r * 512;
        float s = p[0];
#pragma unroll
        for (int ks = 1; ks < 6; ks++) s += p[(size_t)ks * CH5];
        float v = s * scl + bb;
        v = v > 0.f ? v : 0.2f * v;
        ym = fmaxf(ym, v);
    }
    if (h == 1) red2[c] = ym;
    __syncthreads();
    if (h == 0) {
        float m = fmaxf(ym, red2[c]);
        atomicMax(&pooledU[z * 512 + o], ordf(m));
    }
}

// ---------------- final linear: coalesced wave-per-output ----------------
__global__ void k_final(const unsigned* __restrict__ pooledU, const void* __restrict__ We,
                        void* __restrict__ out, const int* __restrict__ flag) {
    __shared__ float p[512];
    int isf = *flag;
    int b = blockIdx.x >> 2, fb = blockIdx.x & 3;
    int t = threadIdx.x, w = t >> 6, l = t & 63;
    for (int i = t; i < 512; i += 256) p[i] = iordf(pooledU[b * 512 + i]);
    __syncthreads();
    for (int it = 0; it < 16; it++) {
        int f = fb * 64 + w * 16 + it;
        float s = 0.f;
        size_t base = (size_t)f * 512 + l * 8;
#pragma unroll
        for (int j = 0; j < 8; j++) s += p[l * 8 + j] * ldw(We, base + j, isf);
#pragma unroll
        for (int off = 32; off > 0; off >>= 1) s += __shfl_down(s, off);
        if (l == 0) {
            if (isf) ((float*)out)[b * 256 + f] = s;
            else     ((bf16*)out)[b * 256 + f] = f2b(s);
        }
    }
}

extern "C" void kernel_launch(void* const* d_in, const int* in_sizes, int n_in,
                              void* d_out, int out_size, void* d_ws, size_t ws_size,
                              hipStream_t stream) {
    const void* x  = d_in[0];
    const void* Wl[4] = { d_in[1], d_in[4], d_in[7], d_in[10] };
    const void* gl[4] = { d_in[2], d_in[5], d_in[8], d_in[11] };
    const void* bl[4] = { d_in[3], d_in[6], d_in[9], d_in[12] };
    const void* W5 = d_in[13];
    const void* g5 = d_in[14];
    const void* b5 = d_in[15];
    const void* We = d_in[16];

    // workspace layout (bytes), ~103.9 MB total
    char* base = (char*)d_ws;
    bf16*     xc_hi   = (bf16*)(base);                  // 7,864,320
    bf16*     xc_lo   = (bf16*)(base + 7864320);        // 7,864,320
    bf16*     xpadh   = (bf16*)(base + 15728640);       // 262,144
    bf16*     xpadl   = (bf16*)(base + 15990784);       // 262,144
    float*    Dbuf    = (float*)(base + 16252928);      // 16,777,216
    float*    Pbuf    = (float*)(base + 33030144);      // 16,777,216
    bf16*     Whi     = (bf16*)(base + 49807360);       // 1,679,360
    bf16*     Wlo     = (bf16*)(base + 51486720);       // 1,679,360
    unsigned* pooledU = (unsigned*)(base + 53493760);   // 8,192
    float*    sq      = (float*)(base + 53501952);      // 16,384
    int*      flag    = (int*)(base + 53518336);        // 4
    float*    P5      = (float*)(base + 53520384);      // 50,331,648 (6 x 8 MB conv5 partials)

    const int Kpad[4]   = { 32, 64, 128, 256 };
    const int Os[4]     = { 64, 128, 256, 512 };
    const int Woff[5]   = { 0, 4096, 20480, 86016, 348160 };
    const int colIn[4]  = { 0, 0, 64, 192 };
    const int colOut[4] = { 0, 64, 192, 448 };

    k_prep<<<3296, 256, 0, stream>>>(Wl[0], Wl[1], Wl[2], Wl[3], W5, x,
                                     Whi, Wlo, xpadh, xpadl, sq, flag, pooledU);

    for (int l = 0; l < 4; l++) {
        int O = Os[l];
        int nCol = (2 * O) >> 7;
        int nBlk = 36 + 8 * nCol;  // 44/52/68/100 -> *4 divisible by 8 for XCD decode
        const bf16* Xh = (l == 0) ? xpadh : (xc_hi + colIn[l]);
        const bf16* Xl = (l == 0) ? xpadl : (xc_lo + colIn[l]);
        int ld = (l == 0) ? 32 : 960;
        size_t xstr = (l == 0) ? (size_t)NPTS * 32 : (size_t)NPTS * 960;
        k_layer_a<<<nBlk * NB, 256, 0, stream>>>(
            Xh, Xl, ld, Kpad[l], xstr, Whi + Woff[l], Wlo + Woff[l], O, sq, Dbuf, Pbuf, flag);
        k_layer_b<<<NPTS * NB / 4, 256, 0, stream>>>(
            Dbuf, Pbuf, gl[l], bl[l], O, xc_hi + colOut[l], xc_lo + colOut[l], sq, l < 3, flag);
    }
    k_conv5<<<768, 256, 0, stream>>>(xc_hi, xc_lo, Whi + Woff[4], Wlo + Woff[4], P5, flag);
    k_pool5<<<512, 256, 0, stream>>>(P5, g5, b5, pooledU, flag);
    k_final<<<16, 256, 0, stream>>>(pooledU, We, d_out, flag);
}

// Round 19
// 276.738 us; speedup vs baseline: 1.6428x; 1.0222x over previous
//
#include <hip/hip_runtime.h>
#include <hip/hip_bf16.h>
#include <math.h>

typedef __hip_bfloat16 bf16;
typedef __bf16 v8bf __attribute__((ext_vector_type(8)));
typedef float v4f __attribute__((ext_vector_type(4)));

#define BN_SCALE 0.9999950000374997f
#define NPTS 1024
#define NB 4
#define CH5 ((size_t)4 * 1024 * 512)   // conv5 partial-chunk stride (floats)

__device__ __forceinline__ float b2f(bf16 v) { return __bfloat162float(v); }
__device__ __forceinline__ bf16 f2b(float v) { return __float2bfloat16(v); }
__device__ __forceinline__ float ldw(const void* p, size_t i, int isf) {
    return isf ? ((const float*)p)[i] : b2f(((const bf16*)p)[i]);
}
__device__ __forceinline__ unsigned ordf(float f) {
    unsigned u = __float_as_uint(f);
    return (u & 0x80000000u) ? ~u : (u | 0x80000000u);
}
__device__ __forceinline__ float iordf(unsigned u) {
    return (u & 0x80000000u) ? __uint_as_float(u ^ 0x80000000u) : __uint_as_float(~u);
}

// per-block dtype detect from first 512 shorts of x (fp32 ~113/256 implausible, bf16 ~0)
__device__ __forceinline__ int detect_isf(const void* xraw, int* cnt) {
    const unsigned short* u = (const unsigned short*)xraw;
    int t = threadIdx.x, c = 0;
    for (int i = t; i < 512; i += 256) {
        unsigned short v = u[i];
        int e = (v >> 7) & 0xFF;
        int m = v & 0x7F;
        if (e == 0xFF || e >= 141 || (e == 0 && m != 0)) c++;
    }
    cnt[t] = c;
    __syncthreads();
    for (int off = 128; off > 0; off >>= 1) {
        if (t < off) cnt[t] += cnt[t + off];
        __syncthreads();
    }
    int isf = (cnt[0] > 30) ? 1 : 0;
    __syncthreads();
    return isf;
}

// ---------------- fused prep: dtype flag + pooled init + weight splits + x pad + sq ----------------
// r/c computed per-branch with LITERAL divisors (shifts / magic-mul for 960): integer-exact,
// avoids the runtime-divisor float-rcp sequence for 840K threads.
__global__ void k_prep(const void* __restrict__ W1, const void* __restrict__ W2,
                       const void* __restrict__ W3, const void* __restrict__ W4,
                       const void* __restrict__ W5, const void* __restrict__ x,
                       bf16* __restrict__ Whi, bf16* __restrict__ Wlo,
                       bf16* __restrict__ xph, bf16* __restrict__ xpl, float* __restrict__ sq,
                       int* __restrict__ flag, unsigned* __restrict__ pooledU) {
    __shared__ int cnt[256];
    int isf = detect_isf(x, cnt);
    if (blockIdx.x == 0) {
        if (threadIdx.x == 0) *flag = isf;
        for (int i = threadIdx.x; i < 2048; i += 256) pooledU[i] = 0u;  // 0 < ordf(any finite)
    }
    int idx = blockIdx.x * 256 + threadIdx.x;
    if (idx < 839680) {
        const void* src; int C, O, two, r, c;
        if (idx < 4096)        { src = W1; C = 3;   O = 64;  two = 1; int lo = idx;          r = lo >> 5; c = lo & 31; }
        else if (idx < 20480)  { src = W2; C = 64;  O = 128; two = 1; int lo = idx - 4096;   r = lo >> 6; c = lo & 63; }
        else if (idx < 86016)  { src = W3; C = 128; O = 256; two = 1; int lo = idx - 20480;  r = lo >> 7; c = lo & 127; }
        else if (idx < 348160) { src = W4; C = 256; O = 512; two = 1; int lo = idx - 86016;  r = lo >> 8; c = lo & 255; }
        else                   { src = W5; C = 960; O = 512; two = 0; int lo = idx - 348160; r = lo / 960; c = lo - r * 960; }
        float wv = 0.f;
        if (c < C) {
            size_t off;
            if (two) off = (r < O) ? (size_t)r * 2 * C + c : (size_t)(r - O) * 2 * C + C + c;
            else     off = (size_t)r * C + c;
            wv = ldw(src, off, isf);
        }
        bf16 h = f2b(wv);
        Whi[idx] = h;
        Wlo[idx] = f2b(wv - b2f(h));
    } else if (idx < 843776) {
        int p = idx - 839680;       // point index: z*1024 + n
        int z = p >> 10, n = p & 1023;
        bf16* ph = xph + (size_t)z * NPTS * 32;
        bf16* pl = xpl + (size_t)z * NPTS * 32;
        float s = 0.f;
        for (int c = 0; c < 32; c++) {
            float v = (c < 3) ? ldw(x, (size_t)z * NPTS * 3 + n * 3 + c, isf) : 0.f;
            bf16 h = f2b(v);
            ph[n * 32 + c] = h;
            pl[n * 32 + c] = f2b(v - b2f(h));
            s += v * v;
        }
        sq[z * NPTS + n] = s;
    }
}

// ---- conflict-free LDS layout: k-quad-major [kq][row][8], XOR-swizzled ----
__device__ __forceinline__ int lidx(int plane, int row) {
    return ((((plane << 7) | row)) ^ (plane << 1)) << 3;
}
// staged fill split: global->regs (issue early) then regs->LDS (write late) for dbuf pipelining
struct St2 { float4 a, b; };
__device__ __forceinline__ St2 ldStage(const bf16* src, int ld) {
    int t = threadIdx.x; int r = t >> 2, kq = t & 3;
    St2 s;
    s.a = *(const float4*)(src + (size_t)r * ld + kq * 8);
    s.b = *(const float4*)(src + (size_t)(r + 64) * ld + kq * 8);
    return s;
}
__device__ __forceinline__ void stStage(bf16* dst, const St2& s) {
    int t = threadIdx.x; int r = t >> 2, kq = t & 3;
    *(float4*)(dst + lidx(kq, r)) = s.a;
    *(float4*)(dst + lidx(kq, r + 64)) = s.b;
}
// single-shot fill (conv5 keeps the proven 2-barrier structure)
__device__ __forceinline__ void fill128(bf16* dst, const bf16* src, int ld) {
    int t = threadIdx.x;
    int r = t >> 2, kq = t & 3;
    *(float4*)(dst + lidx(kq, r))      = *(const float4*)(src + (size_t)r * ld + kq * 8);
    *(float4*)(dst + lidx(kq, r + 64)) = *(const float4*)(src + (size_t)(r + 64) * ld + kq * 8);
}
// MFMA fragment: sub-tile 'sub' (16 rows of 128), lane l: row=sub*16+(l&15), k=(l>>4)*8..+7
__device__ __forceinline__ v8bf ldf(const bf16* tile, int sub, int l) {
    return *(const v8bf*)(tile + lidx(l >> 4, sub * 16 + (l & 15)));
}

#define TSTRIDE 129   // f32 transpose tile stride (128+1: conflict-free row reads)

// ---------------- fused layer stage A: dist (upper-tri 128x128 tiles) + st ----------------
// 1D grid, XCD-pinned: z = (i>>1)&3, bi = ((i>>3)<<1)|(i&1). Double-buffered K-loop;
// dist mirror write via LDS transpose (coalesced both orientations).
__global__ __launch_bounds__(256) void k_layer_a(const bf16* __restrict__ Xhi, const bf16* __restrict__ Xlo,
                                                 int ld, int Kpad, size_t xstride,
                                                 const bf16* __restrict__ Whi, const bf16* __restrict__ Wlo,
                                                 int O, const float* __restrict__ sqg,
                                                 float* __restrict__ Dg, float* __restrict__ Pg,
                                                 const int* __restrict__ flag) {
    int i = blockIdx.x;
    int z = (i >> 1) & 3;
    int bi = ((i >> 3) << 1) | (i & 1);
    const bf16* Xh = Xhi + (size_t)z * xstride;
    const bf16* Xl = Xlo + (size_t)z * xstride;
    __shared__ alignas(16) char smem[128 * TSTRIDE * 4];   // 66,048 B >= 64 KB staging
    bf16* Ah = (bf16*)smem;                 // [2][4096]
    bf16* Al = (bf16*)(smem + 16384);       // [2][4096]
    bf16* Bh = (bf16*)(smem + 32768);       // [2][4096]
    bf16* Bl = (bf16*)(smem + 49152);       // [2][4096]
    int w = threadIdx.x >> 6, l = threadIdx.x & 63;
    int wr = w >> 1, wc = w & 1;
    int quad = l >> 4, col = l & 15;
    v4f zero = {0.f, 0.f, 0.f, 0.f};
    v4f acc[4][4] = {{zero, zero, zero, zero}, {zero, zero, zero, zero},
                     {zero, zero, zero, zero}, {zero, zero, zero, zero}};

    if (bi < 36) {
        // ---- dist tile: triangular decode over 8x8, bx >= by ----
        int bx = 0;
        while ((((bx + 1) * (bx + 2)) >> 1) <= bi) bx++;
        int by = bi - ((bx * (bx + 1)) >> 1);
        const float* sq = sqg + z * NPTS;
        float* D = Dg + (size_t)z * NPTS * NPTS;
        int n0 = by * 128, m0 = bx * 128;
        const bf16* pAn = Xh + (size_t)n0 * ld;
        const bf16* pAm = Xh + (size_t)m0 * ld;
        const bf16* pLn = Xl + (size_t)n0 * ld;
        const bf16* pLm = Xl + (size_t)m0 * ld;
        St2 sA = ldStage(pAn, ld), sB = ldStage(pAm, ld);
        St2 sC = ldStage(pLn, ld), sD = ldStage(pLm, ld);
        stStage(Ah, sA); stStage(Bh, sB);
        stStage(Al, sC); stStage(Bl, sD);
        __syncthreads();
        int cur = 0;
        for (int k0 = 0; k0 < Kpad; k0 += 32) {
            bool more = (k0 + 32 < Kpad);
            if (more) {
                sA = ldStage(pAn + k0 + 32, ld);
                sB = ldStage(pAm + k0 + 32, ld);
                sC = ldStage(pLn + k0 + 32, ld);
                sD = ldStage(pLm + k0 + 32, ld);
            }
            v8bf ah[4], al[4];
#pragma unroll
            for (int mi = 0; mi < 4; mi++) {
                ah[mi] = ldf(Ah + cur * 4096, wr * 4 + mi, l);
                al[mi] = ldf(Al + cur * 4096, wr * 4 + mi, l);
            }
#pragma unroll
            for (int ni = 0; ni < 4; ni++) {
                v8bf bh = ldf(Bh + cur * 4096, wc * 4 + ni, l);
                v8bf bl = ldf(Bl + cur * 4096, wc * 4 + ni, l);
#pragma unroll
                for (int mi = 0; mi < 4; mi++) {
                    acc[mi][ni] = __builtin_amdgcn_mfma_f32_16x16x32_bf16(ah[mi], bh, acc[mi][ni], 0, 0, 0);
                    acc[mi][ni] = __builtin_amdgcn_mfma_f32_16x16x32_bf16(ah[mi], bl, acc[mi][ni], 0, 0, 0);
                    acc[mi][ni] = __builtin_amdgcn_mfma_f32_16x16x32_bf16(al[mi], bh, acc[mi][ni], 0, 0, 0);
                }
            }
            if (more) {
                stStage(Ah + (cur ^ 1) * 4096, sA); stStage(Bh + (cur ^ 1) * 4096, sB);
                stStage(Al + (cur ^ 1) * 4096, sC); stStage(Bl + (cur ^ 1) * 4096, sD);
            }
            __syncthreads();
            cur ^= 1;
        }
        int rb = n0 + wr * 64 + quad * 4;
        int cb = m0 + wc * 64 + col;
        int rloc = wr * 64 + quad * 4;       // row index within tile
        int cloc = wc * 64 + col;            // col index within tile
        float* Tt = (float*)smem;            // [128][TSTRIDE] f32, aliases dead staging
        float sm[4];
#pragma unroll
        for (int ni = 0; ni < 4; ni++) sm[ni] = sq[cb + ni * 16];
#pragma unroll
        for (int mi = 0; mi < 4; mi++) {
#pragma unroll
            for (int r = 0; r < 4; r++) {
                int row = rb + mi * 16 + r;
                float sn = sq[row];
#pragma unroll
                for (int ni = 0; ni < 4; ni++) {
                    float d = 2.f * acc[mi][ni][r] - sn - sm[ni];
                    D[(size_t)row * NPTS + cb + ni * 16] = d;
                    if (bx != by)
                        Tt[(cloc + ni * 16) * TSTRIDE + rloc + mi * 16 + r] = d;
                }
            }
        }
        if (bx != by) {                      // coalesced transposed write of the mirror
            __syncthreads();
            int t = threadIdx.x;
            int rl = t & 127, ch = t >> 7;
            float* Dm = D + (size_t)m0 * NPTS + n0;
#pragma unroll 4
            for (int it = 0; it < 64; it++) {
                int cl = it * 2 + ch;
                Dm[(size_t)cl * NPTS + rl] = Tt[cl * TSTRIDE + rl];
            }
        }
    } else {
        // ---- st tile: P[point m, weight-row n] over 2O cols ----
        int isf = *flag;
        int nCol = (2 * O) >> 7;
        int s = bi - 36;
        int n0 = (s % nCol) * 128;   // weight-row tile (over 2O)
        int m0 = (s / nCol) * 128;   // point tile (over 1024)
        int N2 = 2 * O;
        float* P = Pg + (size_t)z * NPTS * N2;
        const bf16* pXh = Xh + (size_t)m0 * ld;
        const bf16* pXl = Xl + (size_t)m0 * ld;
        const bf16* pWh = Whi + (size_t)n0 * Kpad;
        const bf16* pWl = Wlo + (size_t)n0 * Kpad;
        St2 sA = ldStage(pXh, ld), sC = ldStage(pXl, ld);
        St2 sB = ldStage(pWh, Kpad), sD;
        if (isf) sD = ldStage(pWl, Kpad);
        stStage(Ah, sA); stStage(Al, sC); stStage(Bh, sB);
        if (isf) stStage(Bl, sD);
        __syncthreads();
        int cur = 0;
        for (int k0 = 0; k0 < Kpad; k0 += 32) {
            bool more = (k0 + 32 < Kpad);
            if (more) {
                sA = ldStage(pXh + k0 + 32, ld);
                sC = ldStage(pXl + k0 + 32, ld);
                sB = ldStage(pWh + k0 + 32, Kpad);
                if (isf) sD = ldStage(pWl + k0 + 32, Kpad);
            }
            v8bf ah[4], al[4];
#pragma unroll
            for (int mi = 0; mi < 4; mi++) {
                ah[mi] = ldf(Ah + cur * 4096, wr * 4 + mi, l);
                al[mi] = ldf(Al + cur * 4096, wr * 4 + mi, l);
            }
#pragma unroll
            for (int ni = 0; ni < 4; ni++) {
                v8bf bh = ldf(Bh + cur * 4096, wc * 4 + ni, l);
#pragma unroll
                for (int mi = 0; mi < 4; mi++) {
                    acc[mi][ni] = __builtin_amdgcn_mfma_f32_16x16x32_bf16(ah[mi], bh, acc[mi][ni], 0, 0, 0);
                    acc[mi][ni] = __builtin_amdgcn_mfma_f32_16x16x32_bf16(al[mi], bh, acc[mi][ni], 0, 0, 0);
                }
                if (isf) {
                    v8bf bl = ldf(Bl + cur * 4096, wc * 4 + ni, l);
#pragma unroll
                    for (int mi = 0; mi < 4; mi++)
                        acc[mi][ni] = __builtin_amdgcn_mfma_f32_16x16x32_bf16(ah[mi], bl, acc[mi][ni], 0, 0, 0);
                }
            }
            if (more) {
                stStage(Ah + (cur ^ 1) * 4096, sA); stStage(Al + (cur ^ 1) * 4096, sC);
                stStage(Bh + (cur ^ 1) * 4096, sB);
                if (isf) stStage(Bl + (cur ^ 1) * 4096, sD);
            }
            __syncthreads();
            cur ^= 1;
        }
        int rb = m0 + wr * 64 + quad * 4;
        int cb = n0 + wc * 64 + col;
#pragma unroll
        for (int mi = 0; mi < 4; mi++)
#pragma unroll
            for (int r = 0; r < 4; r++) {
                int row = rb + mi * 16 + r;
#pragma unroll
                for (int ni = 0; ni < 4; ni++)
                    P[(size_t)row * N2 + cb + ni * 16] = acc[mi][ni][r];
            }
    }
}

// ---- DPP wave reduce steps (VALU pipe): val-only fmax, idx-only min_u32 ----
template<int CTRL>
__device__ __forceinline__ void dpp_fmax(float& bv) {
    int ov = __builtin_amdgcn_update_dpp(__float_as_int(bv), __float_as_int(bv), CTRL, 0xF, 0xF, false);
    bv = fmaxf(bv, __int_as_float(ov));
}
template<int CTRL>
__device__ __forceinline__ void dpp_umin(unsigned& m) {
    unsigned om = (unsigned)__builtin_amdgcn_update_dpp((int)m, (int)m, CTRL, 0xF, 0xF, false);
    m = m < om ? m : om;
}
#define PICK(va, ja, vb, jb, vo, jo) { bool t_ = (vb) > (va); vo = t_ ? (vb) : (va); jo = t_ ? (jb) : (ja); }

// max/min of 20 via balanced triple-trees (exact: max/min fully assoc+comm; max3-fusable)
__device__ __forceinline__ float max20(const float* v) {
    float a0 = fmaxf(fmaxf(v[0], v[1]), v[2]);
    float a1 = fmaxf(fmaxf(v[3], v[4]), v[5]);
    float a2 = fmaxf(fmaxf(v[6], v[7]), v[8]);
    float a3 = fmaxf(fmaxf(v[9], v[10]), v[11]);
    float a4 = fmaxf(fmaxf(v[12], v[13]), v[14]);
    float a5 = fmaxf(fmaxf(v[15], v[16]), v[17]);
    float a6 = fmaxf(v[18], v[19]);
    float b0 = fmaxf(fmaxf(a0, a1), a2);
    float b1 = fmaxf(fmaxf(a3, a4), a5);
    return fmaxf(fmaxf(b0, b1), a6);
}
__device__ __forceinline__ float min20(const float* v) {
    float a0 = fminf(fminf(v[0], v[1]), v[2]);
    float a1 = fminf(fminf(v[3], v[4]), v[5]);
    float a2 = fminf(fminf(v[6], v[7]), v[8]);
    float a3 = fminf(fminf(v[9], v[10]), v[11]);
    float a4 = fminf(fminf(v[12], v[13]), v[14]);
    float a5 = fminf(fminf(v[15], v[16]), v[17]);
    float a6 = fminf(v[18], v[19]);
    float b0 = fminf(fminf(a0, a1), a2);
    float b1 = fminf(fminf(a3, a4), a5);
    return fminf(fminf(b0, b1), a6);
}

// ---------------- fused stage B: top-20 + gather-max, WAVE-PER-ROW end-to-end ----------------
// Selection: persistent per-lane candidates + split butterfly; phase-2 (min-idx reduce) is
// SKIPPED when exactly one lane holds gmax (ballot/popcount, wave-uniform branch): that lane's
// candidate already carries the lane-local min-idx, and no other lane contains gmax anywhere
// (its local max would equal gmax) -> dynamic readlane broadcasts the exact winner. Ties fall
// back to the unchanged min_u32 butterfly. ids bit-identical in all cases.
__global__ __launch_bounds__(256) void k_layer_b(const float* __restrict__ Dg, const float* __restrict__ Pg,
                                                 const void* __restrict__ g, const void* __restrict__ bias,
                                                 int O, bf16* __restrict__ xhOut, bf16* __restrict__ xlOut,
                                                 float* __restrict__ sqOut, int writeSq,
                                                 const int* __restrict__ flag) {
    __shared__ int ids[4][20];
    int isf = *flag;
    int i = blockIdx.x;
    int z = (i >> 1) & 3;
    int local = ((i >> 3) << 1) | (i & 1);
    int tid = threadIdx.x;
    int wq = tid >> 6, l = tid & 63;
    int row = local * 4 + wq;

    // ---- per-wave register-resident top-20 (lane->index map bi = jj*256+l*4+q bijective
    //      over [0,1024), monotone per lane in scan order -> min-index tie-break) ----
    {
        const float* Dr = Dg + (size_t)z * NPTS * NPTS + (size_t)row * NPTS;
        float v[16];
#pragma unroll
        for (int jj = 0; jj < 4; jj++) {
            float4 f4 = *(const float4*)(Dr + jj * 256 + l * 4);
            v[jj * 4 + 0] = f4.x; v[jj * 4 + 1] = f4.y;
            v[jj * 4 + 2] = f4.z; v[jj * 4 + 3] = f4.w;
        }
        float bmv[4]; int bmj[4];
#pragma unroll
        for (int gg = 0; gg < 4; gg++) {
            float a0, a1; int j0, j1;
            PICK(v[4 * gg + 0], 4 * gg + 0, v[4 * gg + 1], 4 * gg + 1, a0, j0);
            PICK(v[4 * gg + 2], 4 * gg + 2, v[4 * gg + 3], 4 * gg + 3, a1, j1);
            PICK(a0, j0, a1, j1, bmv[gg], bmj[gg]);
        }
        // persistent lane candidate (candv, candi): tree over group winners, global idx map
        float candv; int candj, candi;
        {
            float t0, t1; int s0, s1;
            PICK(bmv[0], bmj[0], bmv[1], bmj[1], t0, s0);
            PICK(bmv[2], bmj[2], bmv[3], bmj[3], t1, s1);
            PICK(t0, s0, t1, s1, candv, candj);
            candi = (candj >> 2) * 256 + l * 4 + (candj & 3);
        }
        for (int s = 0; s < 20; s++) {
            // phase 1: wave max of candidate values (val-only butterfly)
            float bv = candv;
            dpp_fmax<0xB1>(bv);    // quad_perm xor1
            dpp_fmax<0x4E>(bv);    // quad_perm xor2
            dpp_fmax<0x124>(bv);   // row_ror:4
            dpp_fmax<0x128>(bv);   // row_ror:8
            dpp_fmax<0x142>(bv);   // row_bcast15
            dpp_fmax<0x143>(bv);   // row_bcast31 -> lane63 = global max
            float gmax = __int_as_float(__builtin_amdgcn_readlane(__float_as_int(bv), 63));
            // phase 2: winner index. Unique holder (common case): direct dynamic readlane.
            unsigned long long mask = __ballot(candv == gmax);
            int bii;
            if (__popcll(mask) == 1) {
                int srcl = __ffsll((unsigned long long)mask) - 1;
                bii = __builtin_amdgcn_readlane(candi, srcl);
            } else {
                unsigned mi = (candv == gmax) ? (unsigned)candi : 0xFFFFFFFFu;
                dpp_umin<0xB1>(mi);
                dpp_umin<0x4E>(mi);
                dpp_umin<0x124>(mi);
                dpp_umin<0x128>(mi);
                dpp_umin<0x142>(mi);
                dpp_umin<0x143>(mi);   // lane63 = min idx
                bii = __builtin_amdgcn_readlane((int)mi, 63);
            }
            if (l == 0) ids[wq][s] = bii;
            if (candi == bii) {    // unique owner (candi lane-unique): evict + rebuild
                int ej = (bii >> 8) * 4 + (bii & 3);
                int eg = ej >> 2, ek = ej & 3;
#pragma unroll
                for (int gg = 0; gg < 4; gg++) if (gg == eg) {
#pragma unroll
                    for (int kk = 0; kk < 4; kk++)
                        if (kk == ek) v[4 * gg + kk] = -__builtin_inff();
                    float a0, a1; int j0, j1;
                    PICK(v[4 * gg + 0], 4 * gg + 0, v[4 * gg + 1], 4 * gg + 1, a0, j0);
                    PICK(v[4 * gg + 2], 4 * gg + 2, v[4 * gg + 3], 4 * gg + 3, a1, j1);
                    PICK(a0, j0, a1, j1, bmv[gg], bmj[gg]);
                }
                float t0, t1; int s0, s1;
                PICK(bmv[0], bmj[0], bmv[1], bmj[1], t0, s0);
                PICK(bmv[2], bmj[2], bmv[3], bmj[3], t1, s1);
                PICK(t0, s0, t1, s1, candv, candj);
                candi = (candj >> 2) * 256 + l * 4 + (candj & 3);
            }
        }
    }

    // ---- gather + max for THIS wave's row (affine/lrelu AFTER max: exact FP-monotone commute) ----
    int N2 = 2 * O;
    const float* P = Pg + (size_t)z * NPTS * N2;
    int offj[20];
#pragma unroll
    for (int j = 0; j < 20; j++)
        offj[j] = __builtin_amdgcn_readfirstlane(ids[wq][j]) * N2;  // SGPR row bases
    int n = row;
    const float* Pn = P + (size_t)n * N2;
    float tot = 0.f;
    int nc = O >> 6;
    for (int c = 0; c < nc; c++) {
        int o = c * 64 + l;
        float scl = ldw(g, o, isf) * BN_SCALE;
        float bb = ldw(bias, o, isf);
        float tv = Pn[O + o] - Pn[o];
        float vv[20];
#pragma unroll
        for (int j = 0; j < 20; j++) vv[j] = P[offj[j] + o];
        float mx = max20(vv);
        float base;
        if (__ballot(scl < 0.f) != 0) {     // wave-uniform; never taken at BN init (g=1)
            float mn = min20(vv);
            base = (scl >= 0.f ? mx : mn) + tv;
        } else {
            base = mx + tv;                 // all scl >= 0: mn provably unused
        }
        float accv = base * scl + bb;
        accv = accv > 0.f ? accv : 0.2f * accv;
        bf16 hi = f2b(accv);
        bf16 lo = f2b(accv - b2f(hi));
        xhOut[(size_t)z * NPTS * 960 + (size_t)n * 960 + o] = hi;
        xlOut[(size_t)z * NPTS * 960 + (size_t)n * 960 + o] = lo;
        if (writeSq) {
            float xv = b2f(hi) + b2f(lo);
            float s2 = xv * xv;
#pragma unroll
            for (int off = 32; off > 0; off >>= 1) s2 += __shfl_down(s2, off);
            if (l == 0) tot += s2;       // ascending chunk order: same serial FP sum as before
        }
    }
    if (writeSq && l == 0) sqOut[z * NPTS + row] = tot;
}

// ---------------- conv5 via MFMA, K-split x6 (chunks of 160) -> f32 partials ----------------
// 1D grid 768, XCD-pinned: z=(i>>1)&3, rest=((i>>3)<<1)|(i&1) in [0,192):
//   ks = rest>>5 (K-chunk), tile = rest&31: m0=(tile>>2)*128, o0=(tile&3)*128
__global__ __launch_bounds__(256) void k_conv5(const bf16* __restrict__ Xhi, const bf16* __restrict__ Xlo,
                                               const bf16* __restrict__ Whi, const bf16* __restrict__ Wlo,
                                               float* __restrict__ P5,
                                               const int* __restrict__ flag) {
    int isf = *flag;
    int i = blockIdx.x;
    int z = (i >> 1) & 3;
    int rest = ((i >> 3) << 1) | (i & 1);
    int ks = rest >> 5;
    int tile = rest & 31;
    int m0 = (tile >> 2) * 128, o0 = (tile & 3) * 128;
    const bf16* Xh = Xhi + (size_t)z * NPTS * 960;
    const bf16* Xl = Xlo + (size_t)z * NPTS * 960;
    __shared__ alignas(16) bf16 Ah[4096], Al[4096], Bh[4096], Bl[4096];
    int w = threadIdx.x >> 6, l = threadIdx.x & 63;
    int wr = w >> 1, wc = w & 1;
    int quad = l >> 4, col = l & 15;
    v4f zero = {0.f, 0.f, 0.f, 0.f};
    v4f acc[4][4] = {{zero, zero, zero, zero}, {zero, zero, zero, zero},
                     {zero, zero, zero, zero}, {zero, zero, zero, zero}};
    int kbeg = ks * 160, kend = kbeg + 160;
    for (int k0 = kbeg; k0 < kend; k0 += 32) {
        __syncthreads();
        fill128(Ah, Xh + (size_t)m0 * 960 + k0, 960);
        fill128(Al, Xl + (size_t)m0 * 960 + k0, 960);
        fill128(Bh, Whi + (size_t)o0 * 960 + k0, 960);
        if (isf) fill128(Bl, Wlo + (size_t)o0 * 960 + k0, 960);
        __syncthreads();
        v8bf ah[4], al[4];
#pragma unroll
        for (int mi = 0; mi < 4; mi++) {
            ah[mi] = ldf(Ah, wr * 4 + mi, l);
            al[mi] = ldf(Al, wr * 4 + mi, l);
        }
#pragma unroll
        for (int ni = 0; ni < 4; ni++) {
            v8bf bh = ldf(Bh, wc * 4 + ni, l);
#pragma unroll
            for (int mi = 0; mi < 4; mi++) {
                acc[mi][ni] = __builtin_amdgcn_mfma_f32_16x16x32_bf16(ah[mi], bh, acc[mi][ni], 0, 0, 0);
                acc[mi][ni] = __builtin_amdgcn_mfma_f32_16x16x32_bf16(al[mi], bh, acc[mi][ni], 0, 0, 0);
            }
            if (isf) {
                v8bf bl = ldf(Bl, wc * 4 + ni, l);
#pragma unroll
                for (int mi = 0; mi < 4; mi++)
                    acc[mi][ni] = __builtin_amdgcn_mfma_f32_16x16x32_bf16(ah[mi], bl, acc[mi][ni], 0, 0, 0);
            }
        }
    }
    // write f32 partial tile (disjoint per (ks,z,tile) -> no atomics)
    float* Pw = P5 + (size_t)ks * CH5 + (size_t)z * NPTS * 512;
    int rb = m0 + wr * 64 + quad * 4;
    int cb = o0 + wc * 64 + col;
#pragma unroll
    for (int mi = 0; mi < 4; mi++)
#pragma unroll
        for (int r = 0; r < 4; r++) {
            int row = rb + mi * 16 + r;
#pragma unroll
            for (int ni = 0; ni < 4; ni++)
                Pw[(size_t)row * 512 + cb + ni * 16] = acc[mi][ni][r];
        }
}

// ---------------- pool5: sum 6 K-chunks + affine + lrelu + max over rows -> pooled ----------------
// 1D grid 512, XCD-pinned: z=(i>>1)&3, rest=((i>>3)<<1)|(i&1) in [0,128):
//   oc=(rest&3)*128 cols, mc=(rest>>2)*32 rows; thread: col=t&127, half=t>>7 (16 rows each)
__global__ __launch_bounds__(256) void k_pool5(const float* __restrict__ P5,
                                               const void* __restrict__ g, const void* __restrict__ bias,
                                               unsigned* __restrict__ pooledU,
                                               const int* __restrict__ flag) {
    __shared__ float red2[128];
    int isf = *flag;
    int i = blockIdx.x;
    int z = (i >> 1) & 3;
    int rest = ((i >> 3) << 1) | (i & 1);
    int oc = (rest & 3) * 128, mc = (rest >> 2) * 32;
    int t = threadIdx.x;
    int c = t & 127, h = t >> 7;
    int o = oc + c;
    float scl = ldw(g, o, isf) * BN_SCALE;
    float bb = ldw(bias, o, isf);
    const float* p0 = P5 + (size_t)z * NPTS * 512 + (size_t)(mc + h * 16) * 512 + o;
    float ym = -__builtin_inff();
    for (int r = 0; r < 16; r++) {
        const float* p = p0 + (size_t)r * 512;
        float s = p[0];
#pragma unroll
        for (int ks = 1; ks < 6; ks++) s += p[(size_t)ks * CH5];
        float v = s * scl + bb;
        v = v > 0.f ? v : 0.2f * v;
        ym = fmaxf(ym, v);
    }
    if (h == 1) red2[c] = ym;
    __syncthreads();
    if (h == 0) {
        float m = fmaxf(ym, red2[c]);
        atomicMax(&pooledU[z * 512 + o], ordf(m));
    }
}

// ---------------- final linear: coalesced wave-per-output ----------------
__global__ void k_final(const unsigned* __restrict__ pooledU, const void* __restrict__ We,
                        void* __restrict__ out, const int* __restrict__ flag) {
    __shared__ float p[512];
    int isf = *flag;
    int b = blockIdx.x >> 2, fb = blockIdx.x & 3;
    int t = threadIdx.x, w = t >> 6, l = t & 63;
    for (int i = t; i < 512; i += 256) p[i] = iordf(pooledU[b * 512 + i]);
    __syncthreads();
    for (int it = 0; it < 16; it++) {
        int f = fb * 64 + w * 16 + it;
        float s = 0.f;
        size_t base = (size_t)f * 512 + l * 8;
#pragma unroll
        for (int j = 0; j < 8; j++) s += p[l * 8 + j] * ldw(We, base + j, isf);
#pragma unroll
        for (int off = 32; off > 0; off >>= 1) s += __shfl_down(s, off);
        if (l == 0) {
            if (isf) ((float*)out)[b * 256 + f] = s;
            else     ((bf16*)out)[b * 256 + f] = f2b(s);
        }
    }
}

extern "C" void kernel_launch(void* const* d_in, const int* in_sizes, int n_in,
                              void* d_out, int out_size, void* d_ws, size_t ws_size,
                              hipStream_t stream) {
    const void* x  = d_in[0];
    const void* Wl[4] = { d_in[1], d_in[4], d_in[7], d_in[10] };
    const void* gl[4] = { d_in[2], d_in[5], d_in[8], d_in[11] };
    const void* bl[4] = { d_in[3], d_in[6], d_in[9], d_in[12] };
    const void* W5 = d_in[13];
    const void* g5 = d_in[14];
    const void* b5 = d_in[15];
    const void* We = d_in[16];

    // workspace layout (bytes), ~103.9 MB total
    char* base = (char*)d_ws;
    bf16*     xc_hi   = (bf16*)(base);                  // 7,864,320
    bf16*     xc_lo   = (bf16*)(base + 7864320);        // 7,864,320
    bf16*     xpadh   = (bf16*)(base + 15728640);       // 262,144
    bf16*     xpadl   = (bf16*)(base + 15990784);       // 262,144
    float*    Dbuf    = (float*)(base + 16252928);      // 16,777,216
    float*    Pbuf    = (float*)(base + 33030144);      // 16,777,216
    bf16*     Whi     = (bf16*)(base + 49807360);       // 1,679,360
    bf16*     Wlo     = (bf16*)(base + 51486720);       // 1,679,360
    unsigned* pooledU = (unsigned*)(base + 53493760);   // 8,192
    float*    sq      = (float*)(base + 53501952);      // 16,384
    int*      flag    = (int*)(base + 53518336);        // 4
    float*    P5      = (float*)(base + 53520384);      // 50,331,648 (6 x 8 MB conv5 partials)

    const int Kpad[4]   = { 32, 64, 128, 256 };
    const int Os[4]     = { 64, 128, 256, 512 };
    const int Woff[5]   = { 0, 4096, 20480, 86016, 348160 };
    const int colIn[4]  = { 0, 0, 64, 192 };
    const int colOut[4] = { 0, 64, 192, 448 };

    k_prep<<<3296, 256, 0, stream>>>(Wl[0], Wl[1], Wl[2], Wl[3], W5, x,
                                     Whi, Wlo, xpadh, xpadl, sq, flag, pooledU);

    for (int l = 0; l < 4; l++) {
        int O = Os[l];
        int nCol = (2 * O) >> 7;
        int nBlk = 36 + 8 * nCol;  // 44/52/68/100 -> *4 divisible by 8 for XCD decode
        const bf16* Xh = (l == 0) ? xpadh : (xc_hi + colIn[l]);
        const bf16* Xl = (l == 0) ? xpadl : (xc_lo + colIn[l]);
        int ld = (l == 0) ? 32 : 960;
        size_t xstr = (l == 0) ? (size_t)NPTS * 32 : (size_t)NPTS * 960;
        k_layer_a<<<nBlk * NB, 256, 0, stream>>>(
            Xh, Xl, ld, Kpad[l], xstr, Whi + Woff[l], Wlo + Woff[l], O, sq, Dbuf, Pbuf, flag);
        k_layer_b<<<NPTS * NB / 4, 256, 0, stream>>>(
            Dbuf, Pbuf, gl[l], bl[l], O, xc_hi + colOut[l], xc_lo + colOut[l], sq, l < 3, flag);
    }
    k_conv5<<<768, 256, 0, stream>>>(xc_hi, xc_lo, Whi + Woff[4], Wlo + Woff[4], P5, flag);
    k_pool5<<<512, 256, 0, stream>>>(P5, g5, b5, pooledU, flag);
    k_final<<<16, 256, 0, stream>>>(pooledU, We, d_out, flag);
}

// Round 20
// 274.481 us; speedup vs baseline: 1.6563x; 1.0082x over previous
//
#include <hip/hip_runtime.h>
#include <hip/hip_bf16.h>
#include <math.h>

typedef __hip_bfloat16 bf16;
typedef __bf16 v8bf __attribute__((ext_vector_type(8)));
typedef float v4f __attribute__((ext_vector_type(4)));

#define BN_SCALE 0.9999950000374997f
#define NPTS 1024
#define NB 4
#define CH5 ((size_t)4 * 1024 * 512)   // conv5 partial-chunk stride (floats)

__device__ __forceinline__ float b2f(bf16 v) { return __bfloat162float(v); }
__device__ __forceinline__ bf16 f2b(float v) { return __float2bfloat16(v); }
__device__ __forceinline__ float ldw(const void* p, size_t i, int isf) {
    return isf ? ((const float*)p)[i] : b2f(((const bf16*)p)[i]);
}
__device__ __forceinline__ unsigned ordf(float f) {
    unsigned u = __float_as_uint(f);
    return (u & 0x80000000u) ? ~u : (u | 0x80000000u);
}
__device__ __forceinline__ float iordf(unsigned u) {
    return (u & 0x80000000u) ? __uint_as_float(u ^ 0x80000000u) : __uint_as_float(~u);
}

// per-block dtype detect from first 512 shorts of x (fp32 ~113/256 implausible, bf16 ~0)
__device__ __forceinline__ int detect_isf(const void* xraw, int* cnt) {
    const unsigned short* u = (const unsigned short*)xraw;
    int t = threadIdx.x, c = 0;
    for (int i = t; i < 512; i += 256) {
        unsigned short v = u[i];
        int e = (v >> 7) & 0xFF;
        int m = v & 0x7F;
        if (e == 0xFF || e >= 141 || (e == 0 && m != 0)) c++;
    }
    cnt[t] = c;
    __syncthreads();
    for (int off = 128; off > 0; off >>= 1) {
        if (t < off) cnt[t] += cnt[t + off];
        __syncthreads();
    }
    int isf = (cnt[0] > 30) ? 1 : 0;
    __syncthreads();
    return isf;
}

// ---------------- prep1 (tiny): flag + pooled init + W1 split + x pad + sq ----------------
// Only what layer-1 A consumes. The bulk W2-W5 splits ride inside A1's dispatch (idle CUs).
__global__ void k_prep1(const void* __restrict__ W1, const void* __restrict__ x,
                        bf16* __restrict__ Whi, bf16* __restrict__ Wlo,
                        bf16* __restrict__ xph, bf16* __restrict__ xpl, float* __restrict__ sq,
                        int* __restrict__ flag, unsigned* __restrict__ pooledU) {
    __shared__ int cnt[256];
    int isf = detect_isf(x, cnt);
    if (blockIdx.x == 0) {
        if (threadIdx.x == 0) *flag = isf;
        for (int i = threadIdx.x; i < 2048; i += 256) pooledU[i] = 0u;  // 0 < ordf(any finite)
    }
    int idx = blockIdx.x * 256 + threadIdx.x;
    if (idx < 4096) {
        // W1 split: C=3, O=64, Kpad=32, interleaved (two) layout
        int r = idx >> 5, c = idx & 31;
        float wv = 0.f;
        if (c < 3) {
            size_t off = (r < 64) ? (size_t)r * 6 + c : (size_t)(r - 64) * 6 + 3 + c;
            wv = ldw(W1, off, isf);
        }
        bf16 h = f2b(wv);
        Whi[idx] = h;
        Wlo[idx] = f2b(wv - b2f(h));
    } else if (idx < 8192) {
        int p = idx - 4096;         // point index: z*1024 + n
        int z = p >> 10, n = p & 1023;
        bf16* ph = xph + (size_t)z * NPTS * 32;
        bf16* pl = xpl + (size_t)z * NPTS * 32;
        float s = 0.f;
        for (int c = 0; c < 32; c++) {
            float v = (c < 3) ? ldw(x, (size_t)z * NPTS * 3 + n * 3 + c, isf) : 0.f;
            bf16 h = f2b(v);
            ph[n * 32 + c] = h;
            pl[n * 32 + c] = f2b(v - b2f(h));
            s += v * v;
        }
        sq[z * NPTS + n] = s;
    }
}

// ---- conflict-free LDS layout: k-quad-major [kq][row][8], XOR-swizzled ----
__device__ __forceinline__ int lidx(int plane, int row) {
    return ((((plane << 7) | row)) ^ (plane << 1)) << 3;
}
// staged fill split: global->regs (issue early) then regs->LDS (write late) for dbuf pipelining
struct St2 { float4 a, b; };
__device__ __forceinline__ St2 ldStage(const bf16* src, int ld) {
    int t = threadIdx.x; int r = t >> 2, kq = t & 3;
    St2 s;
    s.a = *(const float4*)(src + (size_t)r * ld + kq * 8);
    s.b = *(const float4*)(src + (size_t)(r + 64) * ld + kq * 8);
    return s;
}
__device__ __forceinline__ void stStage(bf16* dst, const St2& s) {
    int t = threadIdx.x; int r = t >> 2, kq = t & 3;
    *(float4*)(dst + lidx(kq, r)) = s.a;
    *(float4*)(dst + lidx(kq, r + 64)) = s.b;
}
// single-shot fill (conv5 keeps the proven 2-barrier structure)
__device__ __forceinline__ void fill128(bf16* dst, const bf16* src, int ld) {
    int t = threadIdx.x;
    int r = t >> 2, kq = t & 3;
    *(float4*)(dst + lidx(kq, r))      = *(const float4*)(src + (size_t)r * ld + kq * 8);
    *(float4*)(dst + lidx(kq, r + 64)) = *(const float4*)(src + (size_t)(r + 64) * ld + kq * 8);
}
// MFMA fragment: sub-tile 'sub' (16 rows of 128), lane l: row=sub*16+(l&15), k=(l>>4)*8..+7
__device__ __forceinline__ v8bf ldf(const bf16* tile, int sub, int l) {
    return *(const v8bf*)(tile + lidx(l >> 4, sub * 16 + (l & 15)));
}

#define TSTRIDE 129   // f32 transpose tile stride (128+1: conflict-free row reads)

// ---------------- fused layer stage A: dist (upper-tri 128x128 tiles) + st ----------------
// 1D grid, XCD-pinned tile decode for i < tileBlocks. Blocks >= tileBlocks (layer-1 dispatch
// only) perform the W2-W5 weight splits on otherwise-idle CUs; stream order guarantees
// completion before layer-2 A reads Whi/Wlo. Same element math as the old k_prep.
__global__ __launch_bounds__(256) void k_layer_a(const bf16* __restrict__ Xhi, const bf16* __restrict__ Xlo,
                                                 int ld, int Kpad, size_t xstride,
                                                 const bf16* __restrict__ Whi, const bf16* __restrict__ Wlo,
                                                 int O, const float* __restrict__ sqg,
                                                 float* __restrict__ Dg, float* __restrict__ Pg,
                                                 const int* __restrict__ flag, int tileBlocks,
                                                 const void* __restrict__ W2, const void* __restrict__ W3,
                                                 const void* __restrict__ W4, const void* __restrict__ W5,
                                                 bf16* __restrict__ WhiAll, bf16* __restrict__ WloAll) {
    if (blockIdx.x >= tileBlocks) {
        // ---- appended W2-W5 split work (idx in [4096, 839680)) ----
        int isf = *flag;
        int idx = (blockIdx.x - tileBlocks) * 256 + threadIdx.x + 4096;
        const void* src; int C, Ow, two, r, c;
        if (idx < 20480)       { src = W2; C = 64;  Ow = 128; two = 1; int lo = idx - 4096;   r = lo >> 6; c = lo & 63; }
        else if (idx < 86016)  { src = W3; C = 128; Ow = 256; two = 1; int lo = idx - 20480;  r = lo >> 7; c = lo & 127; }
        else if (idx < 348160) { src = W4; C = 256; Ow = 512; two = 1; int lo = idx - 86016;  r = lo >> 8; c = lo & 255; }
        else                   { src = W5; C = 960; Ow = 512; two = 0; int lo = idx - 348160; r = lo / 960; c = lo - r * 960; }
        float wv = 0.f;
        if (c < C) {
            size_t off;
            if (two) off = (r < Ow) ? (size_t)r * 2 * C + c : (size_t)(r - Ow) * 2 * C + C + c;
            else     off = (size_t)r * C + c;
            wv = ldw(src, off, isf);
        }
        bf16 h = f2b(wv);
        WhiAll[idx] = h;
        WloAll[idx] = f2b(wv - b2f(h));
        return;
    }
    int i = blockIdx.x;
    int z = (i >> 1) & 3;
    int bi = ((i >> 3) << 1) | (i & 1);
    const bf16* Xh = Xhi + (size_t)z * xstride;
    const bf16* Xl = Xlo + (size_t)z * xstride;
    __shared__ alignas(16) char smem[128 * TSTRIDE * 4];   // 66,048 B >= 64 KB staging
    bf16* Ah = (bf16*)smem;                 // [2][4096]
    bf16* Al = (bf16*)(smem + 16384);       // [2][4096]
    bf16* Bh = (bf16*)(smem + 32768);       // [2][4096]
    bf16* Bl = (bf16*)(smem + 49152);       // [2][4096]
    int w = threadIdx.x >> 6, l = threadIdx.x & 63;
    int wr = w >> 1, wc = w & 1;
    int quad = l >> 4, col = l & 15;
    v4f zero = {0.f, 0.f, 0.f, 0.f};
    v4f acc[4][4] = {{zero, zero, zero, zero}, {zero, zero, zero, zero},
                     {zero, zero, zero, zero}, {zero, zero, zero, zero}};

    if (bi < 36) {
        // ---- dist tile: triangular decode over 8x8, bx >= by ----
        int bx = 0;
        while ((((bx + 1) * (bx + 2)) >> 1) <= bi) bx++;
        int by = bi - ((bx * (bx + 1)) >> 1);
        const float* sq = sqg + z * NPTS;
        float* D = Dg + (size_t)z * NPTS * NPTS;
        int n0 = by * 128, m0 = bx * 128;
        const bf16* pAn = Xh + (size_t)n0 * ld;
        const bf16* pAm = Xh + (size_t)m0 * ld;
        const bf16* pLn = Xl + (size_t)n0 * ld;
        const bf16* pLm = Xl + (size_t)m0 * ld;
        St2 sA = ldStage(pAn, ld), sB = ldStage(pAm, ld);
        St2 sC = ldStage(pLn, ld), sD = ldStage(pLm, ld);
        stStage(Ah, sA); stStage(Bh, sB);
        stStage(Al, sC); stStage(Bl, sD);
        __syncthreads();
        int cur = 0;
        for (int k0 = 0; k0 < Kpad; k0 += 32) {
            bool more = (k0 + 32 < Kpad);
            if (more) {
                sA = ldStage(pAn + k0 + 32, ld);
                sB = ldStage(pAm + k0 + 32, ld);
                sC = ldStage(pLn + k0 + 32, ld);
                sD = ldStage(pLm + k0 + 32, ld);
            }
            v8bf ah[4], al[4];
#pragma unroll
            for (int mi = 0; mi < 4; mi++) {
                ah[mi] = ldf(Ah + cur * 4096, wr * 4 + mi, l);
                al[mi] = ldf(Al + cur * 4096, wr * 4 + mi, l);
            }
#pragma unroll
            for (int ni = 0; ni < 4; ni++) {
                v8bf bh = ldf(Bh + cur * 4096, wc * 4 + ni, l);
                v8bf bl = ldf(Bl + cur * 4096, wc * 4 + ni, l);
#pragma unroll
                for (int mi = 0; mi < 4; mi++) {
                    acc[mi][ni] = __builtin_amdgcn_mfma_f32_16x16x32_bf16(ah[mi], bh, acc[mi][ni], 0, 0, 0);
                    acc[mi][ni] = __builtin_amdgcn_mfma_f32_16x16x32_bf16(ah[mi], bl, acc[mi][ni], 0, 0, 0);
                    acc[mi][ni] = __builtin_amdgcn_mfma_f32_16x16x32_bf16(al[mi], bh, acc[mi][ni], 0, 0, 0);
                }
            }
            if (more) {
                stStage(Ah + (cur ^ 1) * 4096, sA); stStage(Bh + (cur ^ 1) * 4096, sB);
                stStage(Al + (cur ^ 1) * 4096, sC); stStage(Bl + (cur ^ 1) * 4096, sD);
            }
            __syncthreads();
            cur ^= 1;
        }
        int rb = n0 + wr * 64 + quad * 4;
        int cb = m0 + wc * 64 + col;
        int rloc = wr * 64 + quad * 4;       // row index within tile
        int cloc = wc * 64 + col;            // col index within tile
        float* Tt = (float*)smem;            // [128][TSTRIDE] f32, aliases dead staging
        float sm[4];
#pragma unroll
        for (int ni = 0; ni < 4; ni++) sm[ni] = sq[cb + ni * 16];
#pragma unroll
        for (int mi = 0; mi < 4; mi++) {
#pragma unroll
            for (int r = 0; r < 4; r++) {
                int row = rb + mi * 16 + r;
                float sn = sq[row];
#pragma unroll
                for (int ni = 0; ni < 4; ni++) {
                    float d = 2.f * acc[mi][ni][r] - sn - sm[ni];
                    D[(size_t)row * NPTS + cb + ni * 16] = d;
                    if (bx != by)
                        Tt[(cloc + ni * 16) * TSTRIDE + rloc + mi * 16 + r] = d;
                }
            }
        }
        if (bx != by) {                      // coalesced transposed write of the mirror
            __syncthreads();
            int t = threadIdx.x;
            int rl = t & 127, ch = t >> 7;
            float* Dm = D + (size_t)m0 * NPTS + n0;
#pragma unroll 4
            for (int it = 0; it < 64; it++) {
                int cl = it * 2 + ch;
                Dm[(size_t)cl * NPTS + rl] = Tt[cl * TSTRIDE + rl];
            }
        }
    } else {
        // ---- st tile: P[point m, weight-row n] over 2O cols ----
        int isf = *flag;
        int nCol = (2 * O) >> 7;
        int s = bi - 36;
        int n0 = (s % nCol) * 128;   // weight-row tile (over 2O)
        int m0 = (s / nCol) * 128;   // point tile (over 1024)
        int N2 = 2 * O;
        float* P = Pg + (size_t)z * NPTS * N2;
        const bf16* pXh = Xh + (size_t)m0 * ld;
        const bf16* pXl = Xl + (size_t)m0 * ld;
        const bf16* pWh = Whi + (size_t)n0 * Kpad;
        const bf16* pWl = Wlo + (size_t)n0 * Kpad;
        St2 sA = ldStage(pXh, ld), sC = ldStage(pXl, ld);
        St2 sB = ldStage(pWh, Kpad), sD;
        if (isf) sD = ldStage(pWl, Kpad);
        stStage(Ah, sA); stStage(Al, sC); stStage(Bh, sB);
        if (isf) stStage(Bl, sD);
        __syncthreads();
        int cur = 0;
        for (int k0 = 0; k0 < Kpad; k0 += 32) {
            bool more = (k0 + 32 < Kpad);
            if (more) {
                sA = ldStage(pXh + k0 + 32, ld);
                sC = ldStage(pXl + k0 + 32, ld);
                sB = ldStage(pWh + k0 + 32, Kpad);
                if (isf) sD = ldStage(pWl + k0 + 32, Kpad);
            }
            v8bf ah[4], al[4];
#pragma unroll
            for (int mi = 0; mi < 4; mi++) {
                ah[mi] = ldf(Ah + cur * 4096, wr * 4 + mi, l);
                al[mi] = ldf(Al + cur * 4096, wr * 4 + mi, l);
            }
#pragma unroll
            for (int ni = 0; ni < 4; ni++) {
                v8bf bh = ldf(Bh + cur * 4096, wc * 4 + ni, l);
#pragma unroll
                for (int mi = 0; mi < 4; mi++) {
                    acc[mi][ni] = __builtin_amdgcn_mfma_f32_16x16x32_bf16(ah[mi], bh, acc[mi][ni], 0, 0, 0);
                    acc[mi][ni] = __builtin_amdgcn_mfma_f32_16x16x32_bf16(al[mi], bh, acc[mi][ni], 0, 0, 0);
                }
                if (isf) {
                    v8bf bl = ldf(Bl + cur * 4096, wc * 4 + ni, l);
#pragma unroll
                    for (int mi = 0; mi < 4; mi++)
                        acc[mi][ni] = __builtin_amdgcn_mfma_f32_16x16x32_bf16(ah[mi], bl, acc[mi][ni], 0, 0, 0);
                }
            }
            if (more) {
                stStage(Ah + (cur ^ 1) * 4096, sA); stStage(Al + (cur ^ 1) * 4096, sC);
                stStage(Bh + (cur ^ 1) * 4096, sB);
                if (isf) stStage(Bl + (cur ^ 1) * 4096, sD);
            }
            __syncthreads();
            cur ^= 1;
        }
        int rb = m0 + wr * 64 + quad * 4;
        int cb = n0 + wc * 64 + col;
#pragma unroll
        for (int mi = 0; mi < 4; mi++)
#pragma unroll
            for (int r = 0; r < 4; r++) {
                int row = rb + mi * 16 + r;
#pragma unroll
                for (int ni = 0; ni < 4; ni++)
                    P[(size_t)row * N2 + cb + ni * 16] = acc[mi][ni][r];
            }
    }
}

// ---- DPP wave reduce steps (VALU pipe): val-only fmax, idx-only min_u32 ----
template<int CTRL>
__device__ __forceinline__ void dpp_fmax(float& bv) {
    int ov = __builtin_amdgcn_update_dpp(__float_as_int(bv), __float_as_int(bv), CTRL, 0xF, 0xF, false);
    bv = fmaxf(bv, __int_as_float(ov));
}
template<int CTRL>
__device__ __forceinline__ void dpp_umin(unsigned& m) {
    unsigned om = (unsigned)__builtin_amdgcn_update_dpp((int)m, (int)m, CTRL, 0xF, 0xF, false);
    m = m < om ? m : om;
}
#define PICK(va, ja, vb, jb, vo, jo) { bool t_ = (vb) > (va); vo = t_ ? (vb) : (va); jo = t_ ? (jb) : (ja); }

// max/min of 20 via balanced triple-trees (exact: max/min fully assoc+comm; max3-fusable)
__device__ __forceinline__ float max20(const float* v) {
    float a0 = fmaxf(fmaxf(v[0], v[1]), v[2]);
    float a1 = fmaxf(fmaxf(v[3], v[4]), v[5]);
    float a2 = fmaxf(fmaxf(v[6], v[7]), v[8]);
    float a3 = fmaxf(fmaxf(v[9], v[10]), v[11]);
    float a4 = fmaxf(fmaxf(v[12], v[13]), v[14]);
    float a5 = fmaxf(fmaxf(v[15], v[16]), v[17]);
    float a6 = fmaxf(v[18], v[19]);
    float b0 = fmaxf(fmaxf(a0, a1), a2);
    float b1 = fmaxf(fmaxf(a3, a4), a5);
    return fmaxf(fmaxf(b0, b1), a6);
}
__device__ __forceinline__ float min20(const float* v) {
    float a0 = fminf(fminf(v[0], v[1]), v[2]);
    float a1 = fminf(fminf(v[3], v[4]), v[5]);
    float a2 = fminf(fminf(v[6], v[7]), v[8]);
    float a3 = fminf(fminf(v[9], v[10]), v[11]);
    float a4 = fminf(fminf(v[12], v[13]), v[14]);
    float a5 = fminf(fminf(v[15], v[16]), v[17]);
    float a6 = fminf(v[18], v[19]);
    float b0 = fminf(fminf(a0, a1), a2);
    float b1 = fminf(fminf(a3, a4), a5);
    return fminf(fminf(b0, b1), a6);
}

// ---------------- fused stage B: top-20 + gather-max, WAVE-PER-ROW end-to-end ----------------
// Selection: persistent per-lane candidates + split butterfly; phase-2 skipped when exactly one
// lane holds gmax (ballot/popcount). ids bit-identical in all cases.
__global__ __launch_bounds__(256) void k_layer_b(const float* __restrict__ Dg, const float* __restrict__ Pg,
                                                 const void* __restrict__ g, const void* __restrict__ bias,
                                                 int O, bf16* __restrict__ xhOut, bf16* __restrict__ xlOut,
                                                 float* __restrict__ sqOut, int writeSq,
                                                 const int* __restrict__ flag) {
    __shared__ int ids[4][20];
    int isf = *flag;
    int i = blockIdx.x;
    int z = (i >> 1) & 3;
    int local = ((i >> 3) << 1) | (i & 1);
    int tid = threadIdx.x;
    int wq = tid >> 6, l = tid & 63;
    int row = local * 4 + wq;

    {
        const float* Dr = Dg + (size_t)z * NPTS * NPTS + (size_t)row * NPTS;
        float v[16];
#pragma unroll
        for (int jj = 0; jj < 4; jj++) {
            float4 f4 = *(const float4*)(Dr + jj * 256 + l * 4);
            v[jj * 4 + 0] = f4.x; v[jj * 4 + 1] = f4.y;
            v[jj * 4 + 2] = f4.z; v[jj * 4 + 3] = f4.w;
        }
        float bmv[4]; int bmj[4];
#pragma unroll
        for (int gg = 0; gg < 4; gg++) {
            float a0, a1; int j0, j1;
            PICK(v[4 * gg + 0], 4 * gg + 0, v[4 * gg + 1], 4 * gg + 1, a0, j0);
            PICK(v[4 * gg + 2], 4 * gg + 2, v[4 * gg + 3], 4 * gg + 3, a1, j1);
            PICK(a0, j0, a1, j1, bmv[gg], bmj[gg]);
        }
        float candv; int candj, candi;
        {
            float t0, t1; int s0, s1;
            PICK(bmv[0], bmj[0], bmv[1], bmj[1], t0, s0);
            PICK(bmv[2], bmj[2], bmv[3], bmj[3], t1, s1);
            PICK(t0, s0, t1, s1, candv, candj);
            candi = (candj >> 2) * 256 + l * 4 + (candj & 3);
        }
        for (int s = 0; s < 20; s++) {
            float bv = candv;
            dpp_fmax<0xB1>(bv);    // quad_perm xor1
            dpp_fmax<0x4E>(bv);    // quad_perm xor2
            dpp_fmax<0x124>(bv);   // row_ror:4
            dpp_fmax<0x128>(bv);   // row_ror:8
            dpp_fmax<0x142>(bv);   // row_bcast15
            dpp_fmax<0x143>(bv);   // row_bcast31 -> lane63 = global max
            float gmax = __int_as_float(__builtin_amdgcn_readlane(__float_as_int(bv), 63));
            unsigned long long mask = __ballot(candv == gmax);
            int bii;
            if (__popcll(mask) == 1) {
                int srcl = __ffsll((unsigned long long)mask) - 1;
                bii = __builtin_amdgcn_readlane(candi, srcl);
            } else {
                unsigned mi = (candv == gmax) ? (unsigned)candi : 0xFFFFFFFFu;
                dpp_umin<0xB1>(mi);
                dpp_umin<0x4E>(mi);
                dpp_umin<0x124>(mi);
                dpp_umin<0x128>(mi);
                dpp_umin<0x142>(mi);
                dpp_umin<0x143>(mi);   // lane63 = min idx
                bii = __builtin_amdgcn_readlane((int)mi, 63);
            }
            if (l == 0) ids[wq][s] = bii;
            if (candi == bii) {    // unique owner (candi lane-unique): evict + rebuild
                int ej = (bii >> 8) * 4 + (bii & 3);
                int eg = ej >> 2, ek = ej & 3;
#pragma unroll
                for (int gg = 0; gg < 4; gg++) if (gg == eg) {
#pragma unroll
                    for (int kk = 0; kk < 4; kk++)
                        if (kk == ek) v[4 * gg + kk] = -__builtin_inff();
                    float a0, a1; int j0, j1;
                    PICK(v[4 * gg + 0], 4 * gg + 0, v[4 * gg + 1], 4 * gg + 1, a0, j0);
                    PICK(v[4 * gg + 2], 4 * gg + 2, v[4 * gg + 3], 4 * gg + 3, a1, j1);
                    PICK(a0, j0, a1, j1, bmv[gg], bmj[gg]);
                }
                float t0, t1; int s0, s1;
                PICK(bmv[0], bmj[0], bmv[1], bmj[1], t0, s0);
                PICK(bmv[2], bmj[2], bmv[3], bmj[3], t1, s1);
                PICK(t0, s0, t1, s1, candv, candj);
                candi = (candj >> 2) * 256 + l * 4 + (candj & 3);
            }
        }
    }

    // ---- gather + max for THIS wave's row (affine/lrelu AFTER max: exact FP-monotone commute) ----
    int N2 = 2 * O;
    const float* P = Pg + (size_t)z * NPTS * N2;
    int offj[20];
#pragma unroll
    for (int j = 0; j < 20; j++)
        offj[j] = __builtin_amdgcn_readfirstlane(ids[wq][j]) * N2;  // SGPR row bases
    int n = row;
    const float* Pn = P + (size_t)n * N2;
    float tot = 0.f;
    int nc = O >> 6;
    for (int c = 0; c < nc; c++) {
        int o = c * 64 + l;
        float scl = ldw(g, o, isf) * BN_SCALE;
        float bb = ldw(bias, o, isf);
        float tv = Pn[O + o] - Pn[o];
        float vv[20];
#pragma unroll
        for (int j = 0; j < 20; j++) vv[j] = P[offj[j] + o];
        float mx = max20(vv);
        float base;
        if (__ballot(scl < 0.f) != 0) {     // wave-uniform; never taken at BN init (g=1)
            float mn = min20(vv);
            base = (scl >= 0.f ? mx : mn) + tv;
        } else {
            base = mx + tv;                 // all scl >= 0: mn provably unused
        }
        float accv = base * scl + bb;
        accv = accv > 0.f ? accv : 0.2f * accv;
        bf16 hi = f2b(accv);
        bf16 lo = f2b(accv - b2f(hi));
        xhOut[(size_t)z * NPTS * 960 + (size_t)n * 960 + o] = hi;
        xlOut[(size_t)z * NPTS * 960 + (size_t)n * 960 + o] = lo;
        if (writeSq) {
            float xv = b2f(hi) + b2f(lo);
            float s2 = xv * xv;
#pragma unroll
            for (int off = 32; off > 0; off >>= 1) s2 += __shfl_down(s2, off);
            if (l == 0) tot += s2;       // ascending chunk order: same serial FP sum as before
        }
    }
    if (writeSq && l == 0) sqOut[z * NPTS + row] = tot;
}

// ---------------- conv5 via MFMA, K-split x6 (chunks of 160) -> f32 partials ----------------
// 1D grid 768, XCD-pinned: z=(i>>1)&3, rest=((i>>3)<<1)|(i&1) in [0,192):
//   ks = rest>>5 (K-chunk), tile = rest&31: m0=(tile>>2)*128, o0=(tile&3)*128
__global__ __launch_bounds__(256) void k_conv5(const bf16* __restrict__ Xhi, const bf16* __restrict__ Xlo,
                                               const bf16* __restrict__ Whi, const bf16* __restrict__ Wlo,
                                               float* __restrict__ P5,
                                               const int* __restrict__ flag) {
    int isf = *flag;
    int i = blockIdx.x;
    int z = (i >> 1) & 3;
    int rest = ((i >> 3) << 1) | (i & 1);
    int ks = rest >> 5;
    int tile = rest & 31;
    int m0 = (tile >> 2) * 128, o0 = (tile & 3) * 128;
    const bf16* Xh = Xhi + (size_t)z * NPTS * 960;
    const bf16* Xl = Xlo + (size_t)z * NPTS * 960;
    __shared__ alignas(16) bf16 Ah[4096], Al[4096], Bh[4096], Bl[4096];
    int w = threadIdx.x >> 6, l = threadIdx.x & 63;
    int wr = w >> 1, wc = w & 1;
    int quad = l >> 4, col = l & 15;
    v4f zero = {0.f, 0.f, 0.f, 0.f};
    v4f acc[4][4] = {{zero, zero, zero, zero}, {zero, zero, zero, zero},
                     {zero, zero, zero, zero}, {zero, zero, zero, zero}};
    int kbeg = ks * 160, kend = kbeg + 160;
    for (int k0 = kbeg; k0 < kend; k0 += 32) {
        __syncthreads();
        fill128(Ah, Xh + (size_t)m0 * 960 + k0, 960);
        fill128(Al, Xl + (size_t)m0 * 960 + k0, 960);
        fill128(Bh, Whi + (size_t)o0 * 960 + k0, 960);
        if (isf) fill128(Bl, Wlo + (size_t)o0 * 960 + k0, 960);
        __syncthreads();
        v8bf ah[4], al[4];
#pragma unroll
        for (int mi = 0; mi < 4; mi++) {
            ah[mi] = ldf(Ah, wr * 4 + mi, l);
            al[mi] = ldf(Al, wr * 4 + mi, l);
        }
#pragma unroll
        for (int ni = 0; ni < 4; ni++) {
            v8bf bh = ldf(Bh, wc * 4 + ni, l);
#pragma unroll
            for (int mi = 0; mi < 4; mi++) {
                acc[mi][ni] = __builtin_amdgcn_mfma_f32_16x16x32_bf16(ah[mi], bh, acc[mi][ni], 0, 0, 0);
                acc[mi][ni] = __builtin_amdgcn_mfma_f32_16x16x32_bf16(al[mi], bh, acc[mi][ni], 0, 0, 0);
            }
            if (isf) {
                v8bf bl = ldf(Bl, wc * 4 + ni, l);
#pragma unroll
                for (int mi = 0; mi < 4; mi++)
                    acc[mi][ni] = __builtin_amdgcn_mfma_f32_16x16x32_bf16(ah[mi], bl, acc[mi][ni], 0, 0, 0);
            }
        }
    }
    // write f32 partial tile (disjoint per (ks,z,tile) -> no atomics)
    float* Pw = P5 + (size_t)ks * CH5 + (size_t)z * NPTS * 512;
    int rb = m0 + wr * 64 + quad * 4;
    int cb = o0 + wc * 64 + col;
#pragma unroll
    for (int mi = 0; mi < 4; mi++)
#pragma unroll
        for (int r = 0; r < 4; r++) {
            int row = rb + mi * 16 + r;
#pragma unroll
            for (int ni = 0; ni < 4; ni++)
                Pw[(size_t)row * 512 + cb + ni * 16] = acc[mi][ni][r];
        }
}

// ---------------- pool5: sum 6 K-chunks + affine + lrelu + max over rows -> pooled ----------------
// 1D grid 512, XCD-pinned: z=(i>>1)&3, rest=((i>>3)<<1)|(i&1) in [0,128):
//   oc=(rest&3)*128 cols, mc=(rest>>2)*32 rows; thread: col=t&127, half=t>>7 (16 rows each)
__global__ __launch_bounds__(256) void k_pool5(const float* __restrict__ P5,
                                               const void* __restrict__ g, const void* __restrict__ bias,
                                               unsigned* __restrict__ pooledU,
                                               const int* __restrict__ flag) {
    __shared__ float red2[128];
    int isf = *flag;
    int i = blockIdx.x;
    int z = (i >> 1) & 3;
    int rest = ((i >> 3) << 1) | (i & 1);
    int oc = (rest & 3) * 128, mc = (rest >> 2) * 32;
    int t = threadIdx.x;
    int c = t & 127, h = t >> 7;
    int o = oc + c;
    float scl = ldw(g, o, isf) * BN_SCALE;
    float bb = ldw(bias, o, isf);
    const float* p0 = P5 + (size_t)z * NPTS * 512 + (size_t)(mc + h * 16) * 512 + o;
    float ym = -__builtin_inff();
    for (int r = 0; r < 16; r++) {
        const float* p = p0 + (size_t)r * 512;
        float s = p[0];
#pragma unroll
        for (int ks = 1; ks < 6; ks++) s += p[(size_t)ks * CH5];
        float v = s * scl + bb;
        v = v > 0.f ? v : 0.2f * v;
        ym = fmaxf(ym, v);
    }
    if (h == 1) red2[c] = ym;
    __syncthreads();
    if (h == 0) {
        float m = fmaxf(ym, red2[c]);
        atomicMax(&pooledU[z * 512 + o], ordf(m));
    }
}

// ---------------- final linear: coalesced wave-per-output ----------------
__global__ void k_final(const unsigned* __restrict__ pooledU, const void* __restrict__ We,
                        void* __restrict__ out, const int* __restrict__ flag) {
    __shared__ float p[512];
    int isf = *flag;
    int b = blockIdx.x >> 2, fb = blockIdx.x & 3;
    int t = threadIdx.x, w = t >> 6, l = t & 63;
    for (int i = t; i < 512; i += 256) p[i] = iordf(pooledU[b * 512 + i]);
    __syncthreads();
    for (int it = 0; it < 16; it++) {
        int f = fb * 64 + w * 16 + it;
        float s = 0.f;
        size_t base = (size_t)f * 512 + l * 8;
#pragma unroll
        for (int j = 0; j < 8; j++) s += p[l * 8 + j] * ldw(We, base + j, isf);
#pragma unroll
        for (int off = 32; off > 0; off >>= 1) s += __shfl_down(s, off);
        if (l == 0) {
            if (isf) ((float*)out)[b * 256 + f] = s;
            else     ((bf16*)out)[b * 256 + f] = f2b(s);
        }
    }
}

extern "C" void kernel_launch(void* const* d_in, const int* in_sizes, int n_in,
                              void* d_out, int out_size, void* d_ws, size_t ws_size,
                              hipStream_t stream) {
    const void* x  = d_in[0];
    const void* Wl[4] = { d_in[1], d_in[4], d_in[7], d_in[10] };
    const void* gl[4] = { d_in[2], d_in[5], d_in[8], d_in[11] };
    const void* bl[4] = { d_in[3], d_in[6], d_in[9], d_in[12] };
    const void* W5 = d_in[13];
    const void* g5 = d_in[14];
    const void* b5 = d_in[15];
    const void* We = d_in[16];

    // workspace layout (bytes), ~103.9 MB total
    char* base = (char*)d_ws;
    bf16*     xc_hi   = (bf16*)(base);                  // 7,864,320
    bf16*     xc_lo   = (bf16*)(base + 7864320);        // 7,864,320
    bf16*     xpadh   = (bf16*)(base + 15728640);       // 262,144
    bf16*     xpadl   = (bf16*)(base + 15990784);       // 262,144
    float*    Dbuf    = (float*)(base + 16252928);      // 16,777,216
    float*    Pbuf    = (float*)(base + 33030144);      // 16,777,216
    bf16*     Whi     = (bf16*)(base + 49807360);       // 1,679,360
    bf16*     Wlo     = (bf16*)(base + 51486720);       // 1,679,360
    unsigned* pooledU = (unsigned*)(base + 53493760);   // 8,192
    float*    sq      = (float*)(base + 53501952);      // 16,384
    int*      flag    = (int*)(base + 53518336);        // 4
    float*    P5      = (float*)(base + 53520384);      // 50,331,648 (6 x 8 MB conv5 partials)

    const int Kpad[4]   = { 32, 64, 128, 256 };
    const int Os[4]     = { 64, 128, 256, 512 };
    const int Woff[5]   = { 0, 4096, 20480, 86016, 348160 };
    const int colIn[4]  = { 0, 0, 64, 192 };
    const int colOut[4] = { 0, 64, 192, 448 };

    // tiny prep: W1 split + x pad + sq + flag + pooled init (everything layer-1 A consumes)
    k_prep1<<<32, 256, 0, stream>>>(Wl[0], x, Whi, Wlo, xpadh, xpadl, sq, flag, pooledU);

    for (int l = 0; l < 4; l++) {
        int O = Os[l];
        int nCol = (2 * O) >> 7;
        int nBlk = 36 + 8 * nCol;  // 44/52/68/100 -> *4 divisible by 8 for XCD decode
        const bf16* Xh = (l == 0) ? xpadh : (xc_hi + colIn[l]);
        const bf16* Xl = (l == 0) ? xpadl : (xc_lo + colIn[l]);
        int ld = (l == 0) ? 32 : 960;
        size_t xstr = (l == 0) ? (size_t)NPTS * 32 : (size_t)NPTS * 960;
        int tileBlocks = nBlk * NB;
        // layer-1 dispatch carries the W2-W5 splits (3264 extra blocks) on idle CUs;
        // stream order completes them before layer-2 A reads Whi/Wlo.
        int grid = (l == 0) ? tileBlocks + 3264 : tileBlocks;
        k_layer_a<<<grid, 256, 0, stream>>>(
            Xh, Xl, ld, Kpad[l], xstr, Whi + Woff[l], Wlo + Woff[l], O, sq, Dbuf, Pbuf, flag,
            tileBlocks, Wl[1], Wl[2], Wl[3], W5, Whi, Wlo);
        k_layer_b<<<NPTS * NB / 4, 256, 0, stream>>>(
            Dbuf, Pbuf, gl[l], bl[l], O, xc_hi + colOut[l], xc_lo + colOut[l], sq, l < 3, flag);
    }
    k_conv5<<<768, 256, 0, stream>>>(xc_hi, xc_lo, Whi + Woff[4], Wlo + Woff[4], P5, flag);
    k_pool5<<<512, 256, 0, stream>>>(P5, g5, b5, pooledU, flag);
    k_final<<<16, 256, 0, stream>>>(pooledU, We, d_out, flag);
}